// Round 11
// baseline (117.390 us; speedup 1.0000x reference)
//
#include <hip/hip_runtime.h>
#include <stdint.h>

#define NBATCH   8
#define NA       261888
#define PRE      6000
#define PREP     6016
#define NCHUNK   94
#define OUT_CNT  2000
#define NMS_THR  0.7f
#define NBINS    4096
#define NHB      160      // histogrammed bins: [T0S, 4096)
#define T0S      3936     // static pre-threshold bin: E[cands]=10230 >> 6000
#define NSUB     64       // pass1 blocks per batch
#define LCAP     512      // per-block candidate segment (E=160, 28 sigma headroom)
#define ECAP     8
#define SEGCAP   2048
#define J0       3072     // edges computed only for j < J0; scan falls back past it
#define NJT      12       // J0 / 256
#define NTPE     78       // NJT*(NJT+1)/2 tile-pairs

// workspace layout (bytes) — all state (re)written every call; poison-safe
#define OFF_PREF     0ull                      // 8*64*161*4 = 329728
#define OFF_LCNTS    329728ull                 // 8*64*4 = 2048 -> 331776
#define OFF_SLAB     331776ull                 // 8*64*512*8 = 2097152 -> 2428928
#define OFF_CNT      2428928ull                // 8*6016*4 = 192512 -> 2621440
#define OFF_DONE2    2621440ull                // 32 -> 2621472 (zeroed with cnt: 12034 uint4)
#define NZ4          12034
#define OFF_BOXES    2621472ull                // 8*6016*16 = 770048 -> 3391520
#define OFF_EDGES    3391520ull                // 8*6016*8*2 = 770048 -> 4161568

__device__ __forceinline__ int score_bin(float s) {
    int b = (int)(s * 4096.0f);          // *4096 exact (pow2) -> monotone
    return min(max(b, 0), NBINS - 1);
}

__device__ __forceinline__ float iou_of(float4 A, float4 Bv) {
    float ai = (A.z - A.x) * (A.w - A.y);
    float aj = (Bv.z - Bv.x) * (Bv.w - Bv.y);
    float yy1 = fmaxf(A.x, Bv.x), xx1 = fmaxf(A.y, Bv.y);
    float yy2 = fminf(A.z, Bv.z), xx2 = fminf(A.w, Bv.w);
    float inter = fmaxf(yy2 - yy1, 0.f) * fmaxf(xx2 - xx1, 0.f);
    float uni = (ai + aj) - inter;
    return (uni > 0.f) ? inter / uni : 0.f;
}

__device__ __forceinline__ void box_transform(uint64_t keyv, const float4* an4,
                                              const float4* bb4, float4* bx, uint32_t pos) {
    uint32_t aidx = (uint32_t)(keyv & 0xFFFFFFFFu);
    float4 a = an4[aidx];
    float4 d = bb4[aidx];
    float dy = d.x * 0.1f, dx = d.y * 0.1f, dh = d.z * 0.2f, dw = d.w * 0.2f;
    float h = a.z - a.x, w = a.w - a.y;
    float cy = a.x + 0.5f * h;  cy = cy + dy * h;
    float cx = a.y + 0.5f * w;  cx = cx + dx * w;
    h = h * expf(dh);
    w = w * expf(dw);
    float y1 = cy - 0.5f * h, x1 = cx - 0.5f * w;
    float y2 = y1 + h, x2 = x1 + w;
    float4 o;
    o.x = fminf(fmaxf(y1, 0.f), 1.f);
    o.y = fminf(fmaxf(x1, 0.f), 1.f);
    o.z = fminf(fmaxf(y2, 0.f), 1.f);
    o.w = fminf(fmaxf(x2, 0.f), 1.f);
    bx[pos] = o;
}

// ---------------- K1: stream probs -> bin-grouped per-block slabs + prefix ----------------
// Also zeroes cnt+done2 (consumed by K3, two kernel-boundaries later).
__global__ __launch_bounds__(256) void k_pass1(
        const float* __restrict__ probs, uint32_t* __restrict__ pref,
        uint32_t* __restrict__ lcnts, uint64_t* __restrict__ slab,
        uint4* __restrict__ zcnt) {
    __shared__ uint32_t h[NHB];
    __shared__ uint32_t lp[NHB + 1];
    __shared__ uint64_t lkey[LCAP];
    __shared__ uint32_t lcnt;
    int b = blockIdx.y, sub = blockIdx.x, tid = threadIdx.x;
    int blk = b * NSUB + sub;
    {   // zero cnt+done2 (12034 uint4 over 512 blocks x 24)
        int zi = blk * 24 + tid;
        if (tid < 24 && zi < NZ4) zcnt[zi] = make_uint4(0u, 0u, 0u, 0u);
    }
    if (tid < NHB) h[tid] = 0;
    if (tid == 0) lcnt = 0;
    __syncthreads();
    const float4* p4 = (const float4*)(probs + (size_t)b * NA * 2);
    const int total = NA / 2;
    for (int q = sub * 256 + tid; q < total; q += NSUB * 256) {
        float4 v = p4[q];
        #pragma unroll
        for (int k = 0; k < 2; ++k) {
            float s = k ? v.w : v.y;
            int bin = score_bin(s);
            if (bin >= T0S) {                        // ~0.04% of anchors
                atomicAdd(&h[bin - T0S], 1u);
                uint32_t p = atomicAdd(&lcnt, 1u);
                if (p < LCAP) {
                    uint32_t sb = __float_as_uint(s);
                    lkey[p] = ((uint64_t)(~sb) << 32) | (uint32_t)(2 * q + k);
                }
            }
        }
    }
    __syncthreads();
    if (tid == 0) {                                  // ascending-bin local prefix
        uint32_t a = 0;
        for (int i = 0; i < NHB; ++i) { lp[i] = a; a += h[i]; }
        lp[NHB] = a;
    }
    __syncthreads();
    uint32_t* gp = pref + (size_t)blk * (NHB + 1);
    if (tid <= NHB) gp[tid] = lp[tid];
    if (tid == 0) lcnts[blk] = lcnt;                 // raw (overflow detect)
    if (tid < NHB) h[tid] = lp[tid];                 // reuse as running counters
    __syncthreads();
    uint64_t* gs = slab + (size_t)blk * LCAP;
    uint32_t n = min(lcnt, (uint32_t)LCAP);
    for (uint32_t i = tid; i < n; i += 256) {
        uint64_t k = lkey[i];
        float s = __uint_as_float(~(uint32_t)(k >> 32));
        int bi = score_bin(s) - T0S;
        uint32_t pos = atomicAdd(&h[bi], 1u);
        if (pos < LCAP) gs[pos] = k;
    }
}

// ---------------- K2: per-block select recompute + bin collect + sort + transform ----------
__global__ __launch_bounds__(256) void k_binsel(
        const float* __restrict__ probs, const uint32_t* __restrict__ pref,
        const uint32_t* __restrict__ lcnts, const uint64_t* __restrict__ slab,
        const float* __restrict__ rpn_bbox, const float* __restrict__ anchors,
        float* __restrict__ boxes) {
    __shared__ uint32_t hS[NHB];
    __shared__ uint32_t cS[NHB + 1];
    __shared__ uint64_t key[SEGCAP];     // 16 KB
    __shared__ uint32_t hfull[NBINS];    // 16 KB (fallback only)
    __shared__ int Tsh;
    __shared__ uint32_t flag, ccS, baseS;
    int b = blockIdx.y, g = blockIdx.x, tid = threadIdx.x;
    const uint32_t* pb = pref + (size_t)b * NSUB * (NHB + 1);
    if (tid == 0) flag = 0;
    __syncthreads();
    if (tid < NHB) {
        uint32_t s = 0;
        for (int sub = 0; sub < NSUB; ++sub) {
            const uint32_t* pp = pb + (size_t)sub * (NHB + 1);
            s += pp[tid + 1] - pp[tid];
        }
        hS[tid] = s;
    }
    if (tid < NSUB && lcnts[b * NSUB + tid] > LCAP) atomicOr(&flag, 1u);
    __syncthreads();
    if (tid == 0) {
        uint32_t acc = 0;
        cS[NHB] = 0;
        int T = -1;
        for (int i = NHB - 1; i >= 0; --i) {
            acc += hS[i];
            cS[i] = acc;
            if (T < 0 && acc >= PRE) T = T0S + i;
        }
        Tsh = T;
    }
    __syncthreads();
    int T = Tsh;
    const float4* an4 = (const float4*)(anchors + (size_t)b * NA * 4);
    const float4* bb4 = (const float4*)(rpn_bbox + (size_t)b * NA * 4);
    float4* bx = (float4*)(boxes) + (size_t)b * PREP;

    if (flag != 0 || T < 0) {
        // ---- exact fallback (never taken): block g==0 recomputes everything ----
        if (g != 0) return;
        const float4* p4 = (const float4*)(probs + (size_t)b * NA * 2);
        for (int i = tid; i < NBINS; i += 256) hfull[i] = 0;
        __syncthreads();
        for (int q = tid; q < NA / 2; q += 256) {
            float4 v = p4[q];
            atomicAdd(&hfull[score_bin(v.y)], 1u);
            atomicAdd(&hfull[score_bin(v.w)], 1u);
        }
        __syncthreads();
        if (tid == 0) baseS = 0;
        __syncthreads();
        for (int bin = NBINS - 1; bin >= 0; --bin) {
            uint32_t n = hfull[bin];
            uint32_t base = baseS;
            if (base >= PRE) break;
            if (n) {
                int P = 1; while (P < (int)n) P <<= 1;
                if (P > SEGCAP) P = SEGCAP;
                for (int i = tid; i < P; i += 256) key[i] = ~0ull;
                if (tid == 0) ccS = 0;
                __syncthreads();
                for (int q = tid; q < NA / 2; q += 256) {
                    float4 v = p4[q];
                    #pragma unroll
                    for (int k = 0; k < 2; ++k) {
                        float s = k ? v.w : v.y;
                        if (score_bin(s) == bin) {
                            uint32_t pos = atomicAdd(&ccS, 1u);
                            if (pos < (uint32_t)P) {
                                uint32_t sb2 = __float_as_uint(s);
                                key[pos] = ((uint64_t)(~sb2) << 32) | (uint32_t)(2 * q + k);
                            }
                        }
                    }
                }
                __syncthreads();
                for (int kk = 2; kk <= P; kk <<= 1) {
                    for (int j = kk >> 1; j > 0; j >>= 1) {
                        for (int i = tid; i < P; i += 256) {
                            int ixj = i ^ j;
                            if (ixj > i) {
                                uint64_t a = key[i], c = key[ixj];
                                bool up = ((i & kk) == 0);
                                if ((a > c) == up) { key[i] = c; key[ixj] = a; }
                            }
                        }
                        __syncthreads();
                    }
                }
                for (int r = tid; r < (int)n; r += 256) {
                    uint32_t pos = base + (uint32_t)r;
                    if (pos < PRE && r < SEGCAP) box_transform(key[r], an4, bb4, bx, pos);
                }
                __syncthreads();
            }
            if (tid == 0) baseS = base + n;
            __syncthreads();
        }
        return;
    }

    // ---- normal path: bins T+g, T+g+128, ... ----
    for (int bin = T + g; bin < NBINS; bin += 128) {
        int m = bin - T0S;                   // >= 0 since T >= T0S here
        int n = (int)hS[m];
        if (n == 0) continue;
        uint32_t base = cS[m + 1];           // count strictly above this bin
        if (base >= PRE) continue;
        if (n > SEGCAP) n = SEGCAP;
        int P = 1; while (P < n) P <<= 1;
        for (int i = tid; i < P; i += 256) key[i] = ~0ull;
        if (tid == 0) ccS = 0;
        __syncthreads();
        if (tid < NSUB) {                    // collect this bin's entries from all slabs
            const uint32_t* pp = pb + (size_t)tid * (NHB + 1);
            uint32_t s0 = pp[m], s1 = pp[m + 1];
            const uint64_t* gs = slab + (size_t)(b * NSUB + tid) * LCAP;
            for (uint32_t i = s0; i < s1; ++i) {
                uint32_t pos = atomicAdd(&ccS, 1u);
                if (pos < (uint32_t)P) key[pos] = gs[i];
            }
        }
        __syncthreads();
        for (int kk = 2; kk <= P; kk <<= 1) {
            for (int j = kk >> 1; j > 0; j >>= 1) {
                for (int i = tid; i < P; i += 256) {
                    int ixj = i ^ j;
                    if (ixj > i) {
                        uint64_t a = key[i], c = key[ixj];
                        bool up = ((i & kk) == 0);
                        if ((a > c) == up) { key[i] = c; key[ixj] = a; }
                    }
                }
                __syncthreads();
            }
        }
        for (int r = tid; r < n; r += 256) {
            uint32_t pos = base + (uint32_t)r;
            if (pos < PRE) box_transform(key[r], an4, bb4, bx, pos);
        }
        __syncthreads();
    }
}

// ---------------- K3: edges + last-block-per-batch scan ----------------
struct ScanSh {
    uint8_t  cl[PREP];
    uint32_t pr[PREP];
    uint64_t km[NCHUNK];
    uint16_t list[OUT_CNT];
    int      kcs;
};
union EsSh {
    float4 sb[256];
    ScanSh sc;
};

__global__ __launch_bounds__(256) void k_edgescan(
        const float* __restrict__ boxes, uint32_t* __restrict__ cnt,
        uint16_t* __restrict__ edges, uint32_t* __restrict__ done2,
        float* __restrict__ out) {
    __shared__ EsSh sm;
    __shared__ uint32_t rankS;
    int b = blockIdx.y;
    int t = blockIdx.x;
    int tid = threadIdx.x;
    int ti = 0, rem = t;
    while (rem >= NJT - ti) { rem -= NJT - ti; ++ti; }
    int tj = ti + rem;                       // ti <= tj < NJT
    const float4* bx = (const float4*)(boxes) + (size_t)b * PREP;
    sm.sb[tid] = bx[ti * 256 + tid];
    __syncthreads();
    {
        int gj = tj * 256 + tid;
        float4 Jb = bx[gj];
        float jy1 = Jb.x, jx1 = Jb.y, jy2 = Jb.z, jx2 = Jb.w;
        float aj = (jy2 - jy1) * (jx2 - jx1);
        float thr = 0.6f * aj;
        bool diag = (ti == tj);
        uint32_t* cb = cnt + (size_t)b * PREP;
        uint16_t* eb = edges + (size_t)b * PREP * ECAP;
        int gibase = ti * 256;
        #pragma unroll 4
        for (int it = 0; it < 256; ++it) {
            float4 I = sm.sb[it];            // broadcast, conflict-free
            float yy1 = fmaxf(jy1, I.x), xx1 = fmaxf(jx1, I.y);
            float yy2 = fminf(jy2, I.z), xx2 = fminf(jx2, I.w);
            float ih = fmaxf(yy2 - yy1, 0.f), iw = fmaxf(xx2 - xx1, 0.f);
            float inter = ih * iw;
            if (inter > thr) {               // rare path
                int gi = gibase + it;
                if (!diag || gi < gj) {
                    float ai = (I.z - I.x) * (I.w - I.y);
                    float uni = (ai + aj) - inter;   // reference op order
                    float iou = inter / uni;
                    if (iou > NMS_THR) {
                        uint32_t slot = atomicAdd(&cb[gj], 1u);
                        if (slot < ECAP) eb[(size_t)gj * ECAP + slot] = (uint16_t)gi;
                    }
                }
            }
        }
    }
    __syncthreads();
    __threadfence();                         // release: flush this block's writes
    if (tid == 0) rankS = atomicAdd(&done2[b], 1u);
    __syncthreads();
    if (rankS != NTPE - 1) return;
    __threadfence();                         // acquire: invalidate, see peers' writes

    // ---- scan phase (last block of this batch) ----
    const uint32_t* cb = cnt + (size_t)b * PREP;
    const uint32_t* eb32 = (const uint32_t*)(edges + (size_t)b * PREP * ECAP);
    const uint4*    eb128 = (const uint4*)(edges + (size_t)b * PREP * ECAP);
    #pragma unroll 4
    for (int j = tid; j < PREP; j += 256) {
        uint32_t c = cb[j];
        sm.sc.cl[j] = (j < J0) ? (uint8_t)(c > 255u ? 255u : c) : (uint8_t)255;  // 255 = unknown
        sm.sc.pr[j] = eb32[j * 4];           // slots 0,1
    }
    __syncthreads();
    if (tid < 64) {
        int lane = tid;
        int kc = 0;
        for (int c0 = 0; c0 < NCHUNK; ++c0) {
            int base = c0 * 64;
            int j = base + lane;
            bool valid = j < PRE;
            uint64_t word = __ballot(valid);
            int cv = valid ? (int)sm.sc.cl[j] : 0;
            uint32_t prv = sm.sc.pr[j];
            uint4 ev = make_uint4(0u, 0u, 0u, 0u);
            bool manym = (cv >= 3 && cv <= ECAP);
            if (__ballot(manym)) { if (manym) ev = eb128[j]; }
            bool same = false, supB = false;
            bool hard = valid && (cv > ECAP);
            if (valid && cv > 0 && cv <= ECAP) {
                if (cv <= 2) {
                    int p0 = (int)(prv & 0xFFFFu);
                    int p1 = (int)(prv >> 16);
                    bool s1 = (cv == 2) && (p1 >= base);
                    same = (p0 >= base) || s1;
                    if (!same) {
                        supB = ((sm.sc.km[p0 >> 6] >> (p0 & 63)) & 1ull) != 0ull;
                        if (!supB && cv == 2)
                            supB = ((sm.sc.km[p1 >> 6] >> (p1 & 63)) & 1ull) != 0ull;
                    }
                } else {
                    int es[8] = { (int)(ev.x & 0xFFFFu), (int)(ev.x >> 16),
                                  (int)(ev.y & 0xFFFFu), (int)(ev.y >> 16),
                                  (int)(ev.z & 0xFFFFu), (int)(ev.z >> 16),
                                  (int)(ev.w & 0xFFFFu), (int)(ev.w >> 16) };
                    #pragma unroll
                    for (int k = 0; k < 8; ++k)
                        if (k < cv) same = same || (es[k] >= base);
                    if (!same) {
                        #pragma unroll
                        for (int k = 0; k < 8; ++k)
                            if (k < cv && !supB)
                                supB = ((sm.sc.km[es[k] >> 6] >> (es[k] & 63)) & 1ull) != 0ull;
                    }
                }
            }
            word &= ~__ballot(supB);
            uint64_t fix = __ballot(same || hard);
            while (fix) {
                int p = __ffsll((unsigned long long)fix) - 1;
                fix &= fix - 1;
                int jp = base + p;
                int cvp = __shfl(cv, p);
                bool sup = false;
                if (cvp <= ECAP) {
                    uint32_t prp = (uint32_t)__shfl((int)prv, p);
                    uint32_t evx = (uint32_t)__shfl((int)ev.x, p);
                    uint32_t evy = (uint32_t)__shfl((int)ev.y, p);
                    uint32_t evz = (uint32_t)__shfl((int)ev.z, p);
                    uint32_t evw = (uint32_t)__shfl((int)ev.w, p);
                    int es[8];
                    if (cvp <= 2) {
                        es[0] = (int)(prp & 0xFFFFu); es[1] = (int)(prp >> 16);
                        es[2] = es[3] = es[4] = es[5] = es[6] = es[7] = 0;
                    } else {
                        es[0] = (int)(evx & 0xFFFFu); es[1] = (int)(evx >> 16);
                        es[2] = (int)(evy & 0xFFFFu); es[3] = (int)(evy >> 16);
                        es[4] = (int)(evz & 0xFFFFu); es[5] = (int)(evz >> 16);
                        es[6] = (int)(evw & 0xFFFFu); es[7] = (int)(evw >> 16);
                    }
                    #pragma unroll
                    for (int k = 0; k < 8; ++k) {
                        if (k < cvp && !sup) {
                            int e = es[k];
                            bool kept = (e >= base)
                                ? (((word >> (e - base)) & 1ull) != 0ull)
                                : (((sm.sc.km[e >> 6] >> (e & 63)) & 1ull) != 0ull);
                            sup = sup || kept;
                        }
                    }
                } else {
                    float4 J = bx[jp];
                    bool any = false;
                    for (int t2 = lane; t2 < kc; t2 += 64)
                        if (iou_of(bx[sm.sc.list[t2]], J) > NMS_THR) any = true;
                    if (lane < p && ((word >> lane) & 1ull))
                        if (iou_of(bx[base + lane], J) > NMS_THR) any = true;
                    sup = (__ballot(any) != 0ull);
                }
                if (sup) word &= ~(1ull << p);
            }
            sm.sc.km[c0] = word;
            int pos = kc + __popcll(word & ((1ull << lane) - 1ull));
            if (((word >> lane) & 1ull) && pos < OUT_CNT) sm.sc.list[pos] = (uint16_t)j;
            kc += __popcll(word);
            if (kc >= OUT_CNT) { kc = OUT_CNT; break; }
        }
        if (lane == 0) sm.sc.kcs = kc;
    }
    __syncthreads();
    int kc = sm.sc.kcs;
    float4* ob = (float4*)(out) + (size_t)b * OUT_CNT;
    for (int r = tid; r < OUT_CNT; r += 256) {
        float4 o = make_float4(0.f, 0.f, 0.f, 0.f);
        if (r < kc) o = bx[sm.sc.list[r]];
        ob[r] = o;
    }
}

extern "C" void kernel_launch(void* const* d_in, const int* in_sizes, int n_in,
                              void* d_out, int out_size, void* d_ws, size_t ws_size,
                              hipStream_t stream) {
    const float* probs   = (const float*)d_in[0];
    const float* rpnbbox = (const float*)d_in[1];
    const float* anchors = (const float*)d_in[2];
    float* out = (float*)d_out;
    char* ws = (char*)d_ws;

    uint32_t* pref  = (uint32_t*)(ws + OFF_PREF);
    uint32_t* lcnts = (uint32_t*)(ws + OFF_LCNTS);
    uint64_t* slab  = (uint64_t*)(ws + OFF_SLAB);
    uint32_t* cnt   = (uint32_t*)(ws + OFF_CNT);
    uint32_t* done2 = (uint32_t*)(ws + OFF_DONE2);
    float*    boxes = (float*)(ws + OFF_BOXES);
    uint16_t* edges = (uint16_t*)(ws + OFF_EDGES);

    k_pass1<<<dim3(NSUB, NBATCH), 256, 0, stream>>>(probs, pref, lcnts, slab,
                                                    (uint4*)(ws + OFF_CNT));
    k_binsel<<<dim3(128, NBATCH), 256, 0, stream>>>(probs, pref, lcnts, slab,
                                                    rpnbbox, anchors, boxes);
    k_edgescan<<<dim3(NTPE, NBATCH), 256, 0, stream>>>(boxes, cnt, edges, done2, out);
}

// Round 12
// 88.216 us; speedup vs baseline: 1.3307x; 1.3307x over previous
//
#include <hip/hip_runtime.h>
#include <stdint.h>

#define NBATCH   8
#define NA       261888
#define PRE      6000
#define PREP     6016
#define NCHUNK   94
#define OUT_CNT  2000
#define NMS_THR  0.7f
#define NBINS    4096
#define NHB      160      // histogrammed bins: [T0S, 4096)
#define T0S      3936     // static pre-threshold bin: E[cands]=10230 >> 6000
#define NSUB     64       // pass1 blocks per batch
#define LCAP     512      // per-block candidate segment (E=160, 28 sigma headroom)
#define ECAP     8
#define SEGCAP   2048
#define J0       3072     // edges computed only for j < J0; scan falls back past it
#define NJT      12       // J0 / 256
#define NTPE     78       // NJT*(NJT+1)/2 tile-pairs

// workspace layout (bytes) — all state (re)written every call; poison-safe
#define OFF_PREF     0ull                      // 8*64*161*4 = 329728
#define OFF_LCNTS    329728ull                 // 8*64*4 = 2048 -> 331776
#define OFF_SLAB     331776ull                 // 8*64*512*8 = 2097152 -> 2428928
#define OFF_CNT      2428928ull                // 8*6016*4 = 192512 -> 2621440 (12032 uint4)
#define NZ4          12032
#define OFF_BOXES    2621472ull                // 8*6016*16 = 770048 -> 3391520
#define OFF_EDGES    3391520ull                // 8*6016*8*2 = 770048 -> 4161568

__device__ __forceinline__ int score_bin(float s) {
    int b = (int)(s * 4096.0f);          // *4096 exact (pow2) -> monotone
    return min(max(b, 0), NBINS - 1);
}

__device__ __forceinline__ float iou_of(float4 A, float4 Bv) {
    float ai = (A.z - A.x) * (A.w - A.y);
    float aj = (Bv.z - Bv.x) * (Bv.w - Bv.y);
    float yy1 = fmaxf(A.x, Bv.x), xx1 = fmaxf(A.y, Bv.y);
    float yy2 = fminf(A.z, Bv.z), xx2 = fminf(A.w, Bv.w);
    float inter = fmaxf(yy2 - yy1, 0.f) * fmaxf(xx2 - xx1, 0.f);
    float uni = (ai + aj) - inter;
    return (uni > 0.f) ? inter / uni : 0.f;
}

__device__ __forceinline__ void box_transform(uint64_t keyv, const float4* an4,
                                              const float4* bb4, float4* bx, uint32_t pos) {
    uint32_t aidx = (uint32_t)(keyv & 0xFFFFFFFFu);
    float4 a = an4[aidx];
    float4 d = bb4[aidx];
    float dy = d.x * 0.1f, dx = d.y * 0.1f, dh = d.z * 0.2f, dw = d.w * 0.2f;
    float h = a.z - a.x, w = a.w - a.y;
    float cy = a.x + 0.5f * h;  cy = cy + dy * h;
    float cx = a.y + 0.5f * w;  cx = cx + dx * w;
    h = h * expf(dh);
    w = w * expf(dw);
    float y1 = cy - 0.5f * h, x1 = cx - 0.5f * w;
    float y2 = y1 + h, x2 = x1 + w;
    float4 o;
    o.x = fminf(fmaxf(y1, 0.f), 1.f);
    o.y = fminf(fmaxf(x1, 0.f), 1.f);
    o.z = fminf(fmaxf(y2, 0.f), 1.f);
    o.w = fminf(fmaxf(x2, 0.f), 1.f);
    bx[pos] = o;
}

// ---------------- K1: stream probs -> bin-grouped per-block slabs + prefix ----------------
// Also zeroes cnt (consumed by K3, two kernel-boundaries later).
__global__ __launch_bounds__(256) void k_pass1(
        const float* __restrict__ probs, uint32_t* __restrict__ pref,
        uint32_t* __restrict__ lcnts, uint64_t* __restrict__ slab,
        uint4* __restrict__ zcnt) {
    __shared__ uint32_t h[NHB];
    __shared__ uint32_t lp[NHB + 1];
    __shared__ uint64_t lkey[LCAP];
    __shared__ uint32_t lcnt;
    int b = blockIdx.y, sub = blockIdx.x, tid = threadIdx.x;
    int blk = b * NSUB + sub;
    {   // zero cnt (12032 uint4 over 512 blocks x 24)
        int zi = blk * 24 + tid;
        if (tid < 24 && zi < NZ4) zcnt[zi] = make_uint4(0u, 0u, 0u, 0u);
    }
    if (tid < NHB) h[tid] = 0;
    if (tid == 0) lcnt = 0;
    __syncthreads();
    const float4* p4 = (const float4*)(probs + (size_t)b * NA * 2);
    const int total = NA / 2;
    for (int q = sub * 256 + tid; q < total; q += NSUB * 256) {
        float4 v = p4[q];
        #pragma unroll
        for (int k = 0; k < 2; ++k) {
            float s = k ? v.w : v.y;
            int bin = score_bin(s);
            if (bin >= T0S) {                        // ~0.04% of anchors
                atomicAdd(&h[bin - T0S], 1u);
                uint32_t p = atomicAdd(&lcnt, 1u);
                if (p < LCAP) {
                    uint32_t sb = __float_as_uint(s);
                    lkey[p] = ((uint64_t)(~sb) << 32) | (uint32_t)(2 * q + k);
                }
            }
        }
    }
    __syncthreads();
    if (tid == 0) {                                  // ascending-bin local prefix
        uint32_t a = 0;
        for (int i = 0; i < NHB; ++i) { lp[i] = a; a += h[i]; }
        lp[NHB] = a;
    }
    __syncthreads();
    uint32_t* gp = pref + (size_t)blk * (NHB + 1);
    if (tid <= NHB) gp[tid] = lp[tid];
    if (tid == 0) lcnts[blk] = lcnt;                 // raw (overflow detect)
    if (tid < NHB) h[tid] = lp[tid];                 // reuse as running counters
    __syncthreads();
    uint64_t* gs = slab + (size_t)blk * LCAP;
    uint32_t n = min(lcnt, (uint32_t)LCAP);
    for (uint32_t i = tid; i < n; i += 256) {
        uint64_t k = lkey[i];
        float s = __uint_as_float(~(uint32_t)(k >> 32));
        int bi = score_bin(s) - T0S;
        uint32_t pos = atomicAdd(&h[bi], 1u);
        if (pos < LCAP) gs[pos] = k;
    }
}

// ---------------- K2: per-block select recompute + bin collect + sort + transform ----------
__global__ __launch_bounds__(256) void k_binsel(
        const float* __restrict__ probs, const uint32_t* __restrict__ pref,
        const uint32_t* __restrict__ lcnts, const uint64_t* __restrict__ slab,
        const float* __restrict__ rpn_bbox, const float* __restrict__ anchors,
        float* __restrict__ boxes) {
    __shared__ uint32_t hS[NHB];
    __shared__ uint32_t cS[NHB + 1];
    __shared__ uint64_t key[SEGCAP];     // 16 KB
    __shared__ uint32_t hfull[NBINS];    // 16 KB (fallback only)
    __shared__ int Tsh;
    __shared__ uint32_t flag, ccS, baseS;
    int b = blockIdx.y, g = blockIdx.x, tid = threadIdx.x;
    const uint32_t* pb = pref + (size_t)b * NSUB * (NHB + 1);
    if (tid == 0) flag = 0;
    __syncthreads();
    if (tid < NHB) {
        uint32_t s = 0;
        for (int sub = 0; sub < NSUB; ++sub) {
            const uint32_t* pp = pb + (size_t)sub * (NHB + 1);
            s += pp[tid + 1] - pp[tid];
        }
        hS[tid] = s;
    }
    if (tid < NSUB && lcnts[b * NSUB + tid] > LCAP) atomicOr(&flag, 1u);
    __syncthreads();
    if (tid == 0) {
        uint32_t acc = 0;
        cS[NHB] = 0;
        int T = -1;
        for (int i = NHB - 1; i >= 0; --i) {
            acc += hS[i];
            cS[i] = acc;
            if (T < 0 && acc >= PRE) T = T0S + i;
        }
        Tsh = T;
    }
    __syncthreads();
    int T = Tsh;
    const float4* an4 = (const float4*)(anchors + (size_t)b * NA * 4);
    const float4* bb4 = (const float4*)(rpn_bbox + (size_t)b * NA * 4);
    float4* bx = (float4*)(boxes) + (size_t)b * PREP;

    if (flag != 0 || T < 0) {
        // ---- exact fallback (never taken): block g==0 recomputes everything ----
        if (g != 0) return;
        const float4* p4 = (const float4*)(probs + (size_t)b * NA * 2);
        for (int i = tid; i < NBINS; i += 256) hfull[i] = 0;
        __syncthreads();
        for (int q = tid; q < NA / 2; q += 256) {
            float4 v = p4[q];
            atomicAdd(&hfull[score_bin(v.y)], 1u);
            atomicAdd(&hfull[score_bin(v.w)], 1u);
        }
        __syncthreads();
        if (tid == 0) baseS = 0;
        __syncthreads();
        for (int bin = NBINS - 1; bin >= 0; --bin) {
            uint32_t n = hfull[bin];
            uint32_t base = baseS;
            if (base >= PRE) break;
            if (n) {
                int P = 1; while (P < (int)n) P <<= 1;
                if (P > SEGCAP) P = SEGCAP;
                for (int i = tid; i < P; i += 256) key[i] = ~0ull;
                if (tid == 0) ccS = 0;
                __syncthreads();
                for (int q = tid; q < NA / 2; q += 256) {
                    float4 v = p4[q];
                    #pragma unroll
                    for (int k = 0; k < 2; ++k) {
                        float s = k ? v.w : v.y;
                        if (score_bin(s) == bin) {
                            uint32_t pos = atomicAdd(&ccS, 1u);
                            if (pos < (uint32_t)P) {
                                uint32_t sb2 = __float_as_uint(s);
                                key[pos] = ((uint64_t)(~sb2) << 32) | (uint32_t)(2 * q + k);
                            }
                        }
                    }
                }
                __syncthreads();
                for (int kk = 2; kk <= P; kk <<= 1) {
                    for (int j = kk >> 1; j > 0; j >>= 1) {
                        for (int i = tid; i < P; i += 256) {
                            int ixj = i ^ j;
                            if (ixj > i) {
                                uint64_t a = key[i], c = key[ixj];
                                bool up = ((i & kk) == 0);
                                if ((a > c) == up) { key[i] = c; key[ixj] = a; }
                            }
                        }
                        __syncthreads();
                    }
                }
                for (int r = tid; r < (int)n; r += 256) {
                    uint32_t pos = base + (uint32_t)r;
                    if (pos < PRE && r < SEGCAP) box_transform(key[r], an4, bb4, bx, pos);
                }
                __syncthreads();
            }
            if (tid == 0) baseS = base + n;
            __syncthreads();
        }
        return;
    }

    // ---- normal path: bins T+g, T+g+128, ... ----
    for (int bin = T + g; bin < NBINS; bin += 128) {
        int m = bin - T0S;                   // >= 0 since T >= T0S here
        int n = (int)hS[m];
        if (n == 0) continue;
        uint32_t base = cS[m + 1];           // count strictly above this bin
        if (base >= PRE) continue;
        if (n > SEGCAP) n = SEGCAP;
        int P = 1; while (P < n) P <<= 1;
        for (int i = tid; i < P; i += 256) key[i] = ~0ull;
        if (tid == 0) ccS = 0;
        __syncthreads();
        if (tid < NSUB) {                    // collect this bin's entries from all slabs
            const uint32_t* pp = pb + (size_t)tid * (NHB + 1);
            uint32_t s0 = pp[m], s1 = pp[m + 1];
        const uint64_t* gs = slab + (size_t)(b * NSUB + tid) * LCAP;
            for (uint32_t i = s0; i < s1; ++i) {
                uint32_t pos = atomicAdd(&ccS, 1u);
                if (pos < (uint32_t)P) key[pos] = gs[i];
            }
        }
        __syncthreads();
        for (int kk = 2; kk <= P; kk <<= 1) {
            for (int j = kk >> 1; j > 0; j >>= 1) {
                for (int i = tid; i < P; i += 256) {
                    int ixj = i ^ j;
                    if (ixj > i) {
                        uint64_t a = key[i], c = key[ixj];
                        bool up = ((i & kk) == 0);
                        if ((a > c) == up) { key[i] = c; key[ixj] = a; }
                    }
                }
                __syncthreads();
            }
        }
        for (int r = tid; r < n; r += 256) {
            uint32_t pos = base + (uint32_t)r;
            if (pos < PRE) box_transform(key[r], an4, bb4, bx, pos);
        }
        __syncthreads();
    }
}

// ---------------- K3: overlap edges — 624 blocks, lean inner loop ----------------
__global__ __launch_bounds__(256) void k_edges(const float* __restrict__ boxes,
                                               uint32_t* __restrict__ cnt,
                                               uint16_t* __restrict__ edges) {
    int b = blockIdx.y;
    int t = blockIdx.x;
    int ti = 0, rem = t;
    while (rem >= NJT - ti) { rem -= NJT - ti; ++ti; }
    int tj = ti + rem;                       // ti <= tj < NJT
    __shared__ float4 sb[256];
    const float4* bx = (const float4*)(boxes) + (size_t)b * PREP;
    sb[threadIdx.x] = bx[ti * 256 + threadIdx.x];
    __syncthreads();
    int gj = tj * 256 + threadIdx.x;
    float4 Jb = bx[gj];
    float jy1 = Jb.x, jx1 = Jb.y, jy2 = Jb.z, jx2 = Jb.w;
    float aj = (jy2 - jy1) * (jx2 - jx1);
    float thr = 0.6f * aj;
    bool diag = (ti == tj);
    uint32_t* cb = cnt + (size_t)b * PREP;
    uint16_t* eb = edges + (size_t)b * PREP * ECAP;
    int gibase = ti * 256;
    #pragma unroll 4
    for (int it = 0; it < 256; ++it) {
        float4 I = sb[it];                   // broadcast, conflict-free
        float yy1 = fmaxf(jy1, I.x), xx1 = fmaxf(jx1, I.y);
        float yy2 = fminf(jy2, I.z), xx2 = fminf(jx2, I.w);
        float ih = fmaxf(yy2 - yy1, 0.f), iw = fmaxf(xx2 - xx1, 0.f);
        float inter = ih * iw;
        if (inter > thr) {                   // rare path
            int gi = gibase + it;
            if (!diag || gi < gj) {
                float ai = (I.z - I.x) * (I.w - I.y);
                float uni = (ai + aj) - inter;   // reference op order
                float iou = inter / uni;
                if (iou > NMS_THR) {
                    uint32_t slot = atomicAdd(&cb[gj], 1u);
                    if (slot < ECAP) eb[(size_t)gj * ECAP + slot] = (uint16_t)gi;
                }
            }
        }
    }
}

// ---------------- K4: keep-scan, lane-parallel resolution ----------------
__global__ __launch_bounds__(256) void k_scan(const float* __restrict__ boxes,
                                              const uint32_t* __restrict__ cnt,
                                              const uint16_t* __restrict__ edges,
                                              float* __restrict__ out) {
    int b = blockIdx.x;
    __shared__ uint8_t  cl[PREP];
    __shared__ uint32_t pr[PREP];
    __shared__ uint64_t km[NCHUNK];
    __shared__ uint16_t list[OUT_CNT];
    __shared__ int kcs;
    int tid = threadIdx.x;
    const uint32_t* cb = cnt + (size_t)b * PREP;
    const uint32_t* eb32 = (const uint32_t*)(edges + (size_t)b * PREP * ECAP);
    const uint4*    eb128 = (const uint4*)(edges + (size_t)b * PREP * ECAP);
    #pragma unroll 4
    for (int j = tid; j < PREP; j += 256) {
        uint32_t c = cb[j];
        cl[j] = (j < J0) ? (uint8_t)(c > 255u ? 255u : c) : (uint8_t)255;  // 255 = unknown
        pr[j] = eb32[j * 4];   // slots 0,1
    }
    __syncthreads();
    const float4* bx = (const float4*)(boxes) + (size_t)b * PREP;
    if (tid < 64) {
        int lane = tid;
        int kc = 0;
        for (int c0 = 0; c0 < NCHUNK; ++c0) {
            int base = c0 * 64;
            int j = base + lane;
            bool valid = j < PRE;
            uint64_t word = __ballot(valid);
            int cv = valid ? (int)cl[j] : 0;
            uint32_t prv = pr[j];
            uint4 ev = make_uint4(0u, 0u, 0u, 0u);
            bool manym = (cv >= 3 && cv <= ECAP);
            if (__ballot(manym)) { if (manym) ev = eb128[j]; }
            bool same = false, supB = false;
            bool hard = valid && (cv > ECAP);
            if (valid && cv > 0 && cv <= ECAP) {
                if (cv <= 2) {
                    int p0 = (int)(prv & 0xFFFFu);
                    int p1 = (int)(prv >> 16);
                    bool s1 = (cv == 2) && (p1 >= base);
                    same = (p0 >= base) || s1;
                    if (!same) {
                        supB = ((km[p0 >> 6] >> (p0 & 63)) & 1ull) != 0ull;
                        if (!supB && cv == 2)
                            supB = ((km[p1 >> 6] >> (p1 & 63)) & 1ull) != 0ull;
                    }
                } else {
                    int es[8] = { (int)(ev.x & 0xFFFFu), (int)(ev.x >> 16),
                                  (int)(ev.y & 0xFFFFu), (int)(ev.y >> 16),
                                  (int)(ev.z & 0xFFFFu), (int)(ev.z >> 16),
                                  (int)(ev.w & 0xFFFFu), (int)(ev.w >> 16) };
                    #pragma unroll
                    for (int k = 0; k < 8; ++k)
                        if (k < cv) same = same || (es[k] >= base);
                    if (!same) {
                        #pragma unroll
                        for (int k = 0; k < 8; ++k)
                            if (k < cv && !supB)
                                supB = ((km[es[k] >> 6] >> (es[k] & 63)) & 1ull) != 0ull;
                    }
                }
            }
            word &= ~__ballot(supB);
            uint64_t fix = __ballot(same || hard);
            while (fix) {
                int p = __ffsll((unsigned long long)fix) - 1;
                fix &= fix - 1;
                int jp = base + p;
                int cvp = __shfl(cv, p);
                bool sup = false;
                if (cvp <= ECAP) {
                    uint32_t prp = (uint32_t)__shfl((int)prv, p);
                    uint32_t evx = (uint32_t)__shfl((int)ev.x, p);
                    uint32_t evy = (uint32_t)__shfl((int)ev.y, p);
                    uint32_t evz = (uint32_t)__shfl((int)ev.z, p);
                    uint32_t evw = (uint32_t)__shfl((int)ev.w, p);
                    int es[8];
                    if (cvp <= 2) {
                        es[0] = (int)(prp & 0xFFFFu); es[1] = (int)(prp >> 16);
                        es[2] = es[3] = es[4] = es[5] = es[6] = es[7] = 0;
                    } else {
                        es[0] = (int)(evx & 0xFFFFu); es[1] = (int)(evx >> 16);
                        es[2] = (int)(evy & 0xFFFFu); es[3] = (int)(evy >> 16);
                        es[4] = (int)(evz & 0xFFFFu); es[5] = (int)(evz >> 16);
                        es[6] = (int)(evw & 0xFFFFu); es[7] = (int)(evw >> 16);
                    }
                    #pragma unroll
                    for (int k = 0; k < 8; ++k) {
                        if (k < cvp && !sup) {
                            int e = es[k];
                            bool kept = (e >= base)
                                ? (((word >> (e - base)) & 1ull) != 0ull)
                                : (((km[e >> 6] >> (e & 63)) & 1ull) != 0ull);
                            sup = sup || kept;
                        }
                    }
                } else {
                    float4 J = bx[jp];
                    bool any = false;
                    for (int t2 = lane; t2 < kc; t2 += 64)
                        if (iou_of(bx[list[t2]], J) > NMS_THR) any = true;
                    if (lane < p && ((word >> lane) & 1ull))
                        if (iou_of(bx[base + lane], J) > NMS_THR) any = true;
                    sup = (__ballot(any) != 0ull);
                }
                if (sup) word &= ~(1ull << p);
            }
            km[c0] = word;
            int pos = kc + __popcll(word & ((1ull << lane) - 1ull));
            if (((word >> lane) & 1ull) && pos < OUT_CNT) list[pos] = (uint16_t)j;
            kc += __popcll(word);
            if (kc >= OUT_CNT) { kc = OUT_CNT; break; }
        }
        if (lane == 0) kcs = kc;
    }
    __syncthreads();
    int kc = kcs;
    float4* ob = (float4*)(out) + (size_t)b * OUT_CNT;
    for (int r = tid; r < OUT_CNT; r += 256) {
        float4 o = make_float4(0.f, 0.f, 0.f, 0.f);
        if (r < kc) o = bx[list[r]];
        ob[r] = o;
    }
}

extern "C" void kernel_launch(void* const* d_in, const int* in_sizes, int n_in,
                              void* d_out, int out_size, void* d_ws, size_t ws_size,
                              hipStream_t stream) {
    const float* probs   = (const float*)d_in[0];
    const float* rpnbbox = (const float*)d_in[1];
    const float* anchors = (const float*)d_in[2];
    float* out = (float*)d_out;
    char* ws = (char*)d_ws;

    uint32_t* pref  = (uint32_t*)(ws + OFF_PREF);
    uint32_t* lcnts = (uint32_t*)(ws + OFF_LCNTS);
    uint64_t* slab  = (uint64_t*)(ws + OFF_SLAB);
    uint32_t* cnt   = (uint32_t*)(ws + OFF_CNT);
    float*    boxes = (float*)(ws + OFF_BOXES);
    uint16_t* edges = (uint16_t*)(ws + OFF_EDGES);

    k_pass1<<<dim3(NSUB, NBATCH), 256, 0, stream>>>(probs, pref, lcnts, slab,
                                                    (uint4*)(ws + OFF_CNT));
    k_binsel<<<dim3(128, NBATCH), 256, 0, stream>>>(probs, pref, lcnts, slab,
                                                    rpnbbox, anchors, boxes);
    k_edges<<<dim3(NTPE, NBATCH), 256, 0, stream>>>(boxes, cnt, edges);
    k_scan<<<NBATCH, 256, 0, stream>>>(boxes, cnt, edges, out);
}

// Round 13
// 87.863 us; speedup vs baseline: 1.3360x; 1.0040x over previous
//
#include <hip/hip_runtime.h>
#include <stdint.h>

#define NBATCH   8
#define NA       261888
#define PRE      6000
#define PREP     6016
#define NCHUNK   94
#define OUT_CNT  2000
#define NMS_THR  0.7f
#define NBINS    4096
#define NHB      160      // histogrammed bins: [T0S, 4096)
#define T0S      3936     // static pre-threshold bin: E[cands]=10230 >> 6000
#define NSUB     64       // pass1 blocks per batch
#define LCAP     512      // per-block candidate segment (E=160, 28 sigma headroom)
#define ECAP     8
#define SEGCAP   2048
#define J0       3072     // edges computed only for j < J0; scan falls back past it
#define NJT      12       // J0 / 256
#define NTPE     78       // NJT*(NJT+1)/2 tile-pairs

// workspace layout (bytes) — all state (re)written every call; poison-safe
#define OFF_PREF     0ull                      // 8*64*161*4 = 329728
#define OFF_LCNTS    329728ull                 // 2048 -> 331776
#define OFF_SLAB     331776ull                 // 8*64*512*8 = 2097152 -> 2428928
#define OFF_CNT      2428928ull                // 8*6016*4 = 192512 -> 2621440
#define OFF_DONE2    2621440ull                // 32 -> 2621472  (zeroed with cnt)
#define NZ4          12034                     // (192512+32)/16 uint4s
#define OFF_BOXES    2621472ull                // 8*6016*16 = 770048 -> 3391520
#define OFF_EDGES    3391520ull                // 8*6016*8*4 = 1540096 -> 4931616

__device__ __forceinline__ int score_bin(float s) {
    int b = (int)(s * 4096.0f);          // *4096 exact (pow2) -> monotone
    return min(max(b, 0), NBINS - 1);
}

__device__ __forceinline__ float iou_of(float4 A, float4 Bv) {
    float ai = (A.z - A.x) * (A.w - A.y);
    float aj = (Bv.z - Bv.x) * (Bv.w - Bv.y);
    float yy1 = fmaxf(A.x, Bv.x), xx1 = fmaxf(A.y, Bv.y);
    float yy2 = fminf(A.z, Bv.z), xx2 = fminf(A.w, Bv.w);
    float inter = fmaxf(yy2 - yy1, 0.f) * fmaxf(xx2 - xx1, 0.f);
    float uni = (ai + aj) - inter;
    return (uni > 0.f) ? inter / uni : 0.f;
}

__device__ __forceinline__ void box_transform(uint64_t keyv, const float4* an4,
                                              const float4* bb4, float4* bx, uint32_t pos) {
    uint32_t aidx = (uint32_t)(keyv & 0xFFFFFFFFu);
    float4 a = an4[aidx];
    float4 d = bb4[aidx];
    float dy = d.x * 0.1f, dx = d.y * 0.1f, dh = d.z * 0.2f, dw = d.w * 0.2f;
    float h = a.z - a.x, w = a.w - a.y;
    float cy = a.x + 0.5f * h;  cy = cy + dy * h;
    float cx = a.y + 0.5f * w;  cx = cx + dx * w;
    h = h * expf(dh);
    w = w * expf(dw);
    float y1 = cy - 0.5f * h, x1 = cx - 0.5f * w;
    float y2 = y1 + h, x2 = x1 + w;
    float4 o;
    o.x = fminf(fmaxf(y1, 0.f), 1.f);
    o.y = fminf(fmaxf(x1, 0.f), 1.f);
    o.z = fminf(fmaxf(y2, 0.f), 1.f);
    o.w = fminf(fmaxf(x2, 0.f), 1.f);
    bx[pos] = o;
}

// ---------------- K1: stream probs -> bin-grouped per-block slabs + prefix ----------------
// Also zeroes cnt+done2 (consumed by K3, two kernel-boundaries later).
__global__ __launch_bounds__(256) void k_pass1(
        const float* __restrict__ probs, uint32_t* __restrict__ pref,
        uint32_t* __restrict__ lcnts, uint64_t* __restrict__ slab,
        uint4* __restrict__ zcnt) {
    __shared__ uint32_t h[NHB];
    __shared__ uint32_t lp[NHB + 1];
    __shared__ uint64_t lkey[LCAP];
    __shared__ uint32_t lcnt;
    int b = blockIdx.y, sub = blockIdx.x, tid = threadIdx.x;
    int blk = b * NSUB + sub;
    {   // zero cnt+done2 (12034 uint4 over 512 blocks x 24)
        int zi = blk * 24 + tid;
        if (tid < 24 && zi < NZ4) zcnt[zi] = make_uint4(0u, 0u, 0u, 0u);
    }
    if (tid < NHB) h[tid] = 0;
    if (tid == 0) lcnt = 0;
    __syncthreads();
    const float4* p4 = (const float4*)(probs + (size_t)b * NA * 2);
    const int total = NA / 2;
    for (int q = sub * 256 + tid; q < total; q += NSUB * 256) {
        float4 v = p4[q];
        #pragma unroll
        for (int k = 0; k < 2; ++k) {
            float s = k ? v.w : v.y;
            int bin = score_bin(s);
            if (bin >= T0S) {                        // ~0.04% of anchors
                atomicAdd(&h[bin - T0S], 1u);
                uint32_t p = atomicAdd(&lcnt, 1u);
                if (p < LCAP) {
                    uint32_t sb = __float_as_uint(s);
                    lkey[p] = ((uint64_t)(~sb) << 32) | (uint32_t)(2 * q + k);
                }
            }
        }
    }
    __syncthreads();
    if (tid == 0) {                                  // ascending-bin local prefix
        uint32_t a = 0;
        for (int i = 0; i < NHB; ++i) { lp[i] = a; a += h[i]; }
        lp[NHB] = a;
    }
    __syncthreads();
    uint32_t* gp = pref + (size_t)blk * (NHB + 1);
    if (tid <= NHB) gp[tid] = lp[tid];
    if (tid == 0) lcnts[blk] = lcnt;                 // raw (overflow detect)
    if (tid < NHB) h[tid] = lp[tid];                 // reuse as running counters
    __syncthreads();
    uint64_t* gs = slab + (size_t)blk * LCAP;
    uint32_t n = min(lcnt, (uint32_t)LCAP);
    for (uint32_t i = tid; i < n; i += 256) {
        uint64_t k = lkey[i];
        float s = __uint_as_float(~(uint32_t)(k >> 32));
        int bi = score_bin(s) - T0S;
        uint32_t pos = atomicAdd(&h[bi], 1u);
        if (pos < LCAP) gs[pos] = k;
    }
}

// ---------------- K2: per-block select recompute + bin collect + sort + transform ----------
__global__ __launch_bounds__(256) void k_binsel(
        const float* __restrict__ probs, const uint32_t* __restrict__ pref,
        const uint32_t* __restrict__ lcnts, const uint64_t* __restrict__ slab,
        const float* __restrict__ rpn_bbox, const float* __restrict__ anchors,
        float* __restrict__ boxes) {
    __shared__ uint32_t hS[NHB];
    __shared__ uint32_t cS[NHB + 1];
    __shared__ uint64_t key[SEGCAP];     // 16 KB
    __shared__ uint32_t hfull[NBINS];    // 16 KB (fallback only)
    __shared__ int Tsh;
    __shared__ uint32_t flag, ccS, baseS;
    int b = blockIdx.y, g = blockIdx.x, tid = threadIdx.x;
    const uint32_t* pb = pref + (size_t)b * NSUB * (NHB + 1);
    if (tid == 0) flag = 0;
    __syncthreads();
    if (tid < NHB) {
        uint32_t s = 0;
        for (int sub = 0; sub < NSUB; ++sub) {
            const uint32_t* pp = pb + (size_t)sub * (NHB + 1);
            s += pp[tid + 1] - pp[tid];
        }
        hS[tid] = s;
    }
    if (tid < NSUB && lcnts[b * NSUB + tid] > LCAP) atomicOr(&flag, 1u);
    __syncthreads();
    if (tid == 0) {
        uint32_t acc = 0;
        cS[NHB] = 0;
        int T = -1;
        for (int i = NHB - 1; i >= 0; --i) {
            acc += hS[i];
            cS[i] = acc;
            if (T < 0 && acc >= PRE) T = T0S + i;
        }
        Tsh = T;
    }
    __syncthreads();
    int T = Tsh;
    const float4* an4 = (const float4*)(anchors + (size_t)b * NA * 4);
    const float4* bb4 = (const float4*)(rpn_bbox + (size_t)b * NA * 4);
    float4* bx = (float4*)(boxes) + (size_t)b * PREP;

    if (flag != 0 || T < 0) {
        // ---- exact fallback (never taken): block g==0 recomputes everything ----
        if (g != 0) return;
        const float4* p4 = (const float4*)(probs + (size_t)b * NA * 2);
        for (int i = tid; i < NBINS; i += 256) hfull[i] = 0;
        __syncthreads();
        for (int q = tid; q < NA / 2; q += 256) {
            float4 v = p4[q];
            atomicAdd(&hfull[score_bin(v.y)], 1u);
            atomicAdd(&hfull[score_bin(v.w)], 1u);
        }
        __syncthreads();
        if (tid == 0) baseS = 0;
        __syncthreads();
        for (int bin = NBINS - 1; bin >= 0; --bin) {
            uint32_t n = hfull[bin];
            uint32_t base = baseS;
            if (base >= PRE) break;
            if (n) {
                int P = 1; while (P < (int)n) P <<= 1;
                if (P > SEGCAP) P = SEGCAP;
                for (int i = tid; i < P; i += 256) key[i] = ~0ull;
                if (tid == 0) ccS = 0;
                __syncthreads();
                for (int q = tid; q < NA / 2; q += 256) {
                    float4 v = p4[q];
                    #pragma unroll
                    for (int k = 0; k < 2; ++k) {
                        float s = k ? v.w : v.y;
                        if (score_bin(s) == bin) {
                            uint32_t pos = atomicAdd(&ccS, 1u);
                            if (pos < (uint32_t)P) {
                                uint32_t sb2 = __float_as_uint(s);
                                key[pos] = ((uint64_t)(~sb2) << 32) | (uint32_t)(2 * q + k);
                            }
                        }
                    }
                }
                __syncthreads();
                for (int kk = 2; kk <= P; kk <<= 1) {
                    for (int j = kk >> 1; j > 0; j >>= 1) {
                        for (int i = tid; i < P; i += 256) {
                            int ixj = i ^ j;
                            if (ixj > i) {
                                uint64_t a = key[i], c = key[ixj];
                                bool up = ((i & kk) == 0);
                                if ((a > c) == up) { key[i] = c; key[ixj] = a; }
                            }
                        }
                        __syncthreads();
                    }
                }
                for (int r = tid; r < (int)n; r += 256) {
                    uint32_t pos = base + (uint32_t)r;
                    if (pos < PRE && r < SEGCAP) box_transform(key[r], an4, bb4, bx, pos);
                }
                __syncthreads();
            }
            if (tid == 0) baseS = base + n;
            __syncthreads();
        }
        return;
    }

    // ---- normal path: bins T+g, T+g+128, ... ----
    for (int bin = T + g; bin < NBINS; bin += 128) {
        int m = bin - T0S;                   // >= 0 since T >= T0S here
        int n = (int)hS[m];
        if (n == 0) continue;
        uint32_t base = cS[m + 1];           // count strictly above this bin
        if (base >= PRE) continue;
        if (n > SEGCAP) n = SEGCAP;
        int P = 1; while (P < n) P <<= 1;
        for (int i = tid; i < P; i += 256) key[i] = ~0ull;
        if (tid == 0) ccS = 0;
        __syncthreads();
        if (tid < NSUB) {                    // collect this bin's entries from all slabs
            const uint32_t* pp = pb + (size_t)tid * (NHB + 1);
            uint32_t s0 = pp[m], s1 = pp[m + 1];
            const uint64_t* gs = slab + (size_t)(b * NSUB + tid) * LCAP;
            for (uint32_t i = s0; i < s1; ++i) {
                uint32_t pos = atomicAdd(&ccS, 1u);
                if (pos < (uint32_t)P) key[pos] = gs[i];
            }
        }
        __syncthreads();
        for (int kk = 2; kk <= P; kk <<= 1) {
            for (int j = kk >> 1; j > 0; j >>= 1) {
                for (int i = tid; i < P; i += 256) {
                    int ixj = i ^ j;
                    if (ixj > i) {
                        uint64_t a = key[i], c = key[ixj];
                        bool up = ((i & kk) == 0);
                        if ((a > c) == up) { key[i] = c; key[ixj] = a; }
                    }
                }
                __syncthreads();
            }
        }
        for (int r = tid; r < n; r += 256) {
            uint32_t pos = base + (uint32_t)r;
            if (pos < PRE) box_transform(key[r], an4, bb4, bx, pos);
        }
        __syncthreads();
    }
}

// ---------------- K3: edges (atomic stores) + last-block-per-batch scan (no fences) --------
struct ScanSh {
    uint8_t  cl[PREP];
    uint32_t pr[PREP];
    uint64_t km[NCHUNK];
    uint16_t list[OUT_CNT];
    int      kcs;
};
union EsSh {
    float4 sb[256];
    ScanSh sc;
};

__global__ __launch_bounds__(256) void k_edgescan(
        const float* __restrict__ boxes, uint32_t* __restrict__ cnt,
        uint32_t* __restrict__ edges, uint32_t* __restrict__ done2,
        float* __restrict__ out) {
    __shared__ EsSh sm;
    __shared__ uint32_t rankS;
    int b = blockIdx.y;
    int t = blockIdx.x;
    int tid = threadIdx.x;
    int ti = 0, rem = t;
    while (rem >= NJT - ti) { rem -= NJT - ti; ++ti; }
    int tj = ti + rem;                       // ti <= tj < NJT
    const float4* bx = (const float4*)(boxes) + (size_t)b * PREP;
    sm.sb[tid] = bx[ti * 256 + tid];
    __syncthreads();
    {
        int gj = tj * 256 + tid;
        float4 Jb = bx[gj];
        float jy1 = Jb.x, jx1 = Jb.y, jy2 = Jb.z, jx2 = Jb.w;
        float aj = (jy2 - jy1) * (jx2 - jx1);
        float thr = 0.6f * aj;
        bool diag = (ti == tj);
        uint32_t* cb = cnt + (size_t)b * PREP;
        uint32_t* eb = edges + (size_t)b * PREP * ECAP;
        int gibase = ti * 256;
        #pragma unroll 4
        for (int it = 0; it < 256; ++it) {
            float4 I = sm.sb[it];            // broadcast, conflict-free
            float yy1 = fmaxf(jy1, I.x), xx1 = fmaxf(jx1, I.y);
            float yy2 = fminf(jy2, I.z), xx2 = fminf(jx2, I.w);
            float ih = fmaxf(yy2 - yy1, 0.f), iw = fmaxf(xx2 - xx1, 0.f);
            float inter = ih * iw;
            if (inter > thr) {               // rare path
                int gi = gibase + it;
                if (!diag || gi < gj) {
                    float ai = (I.z - I.x) * (I.w - I.y);
                    float uni = (ai + aj) - inter;   // reference op order
                    float iou = inter / uni;
                    if (iou > NMS_THR) {
                        uint32_t slot = atomicAdd(&cb[gj], 1u);
                        if (slot < ECAP)
                            atomicExch(&eb[(size_t)gj * ECAP + slot], (uint32_t)gi);
                    }
                }
            }
        }
    }
    __syncthreads();                         // vmcnt(0): all this block's atomics completed
    if (tid == 0) rankS = atomicAdd(&done2[b], 1u);
    __syncthreads();
    if (rankS != NTPE - 1) return;
    // last block of batch: all peers' cnt/edge atomics are at the coherence point;
    // this XCD's caches never cached those lines this kernel -> plain loads see them.

    const uint32_t* cb = cnt + (size_t)b * PREP;
    const uint32_t* ebw = edges + (size_t)b * PREP * ECAP;
    #pragma unroll 4
    for (int j = tid; j < PREP; j += 256) {
        uint32_t c = cb[j];
        sm.sc.cl[j] = (j < J0) ? (uint8_t)(c > 255u ? 255u : c) : (uint8_t)255;  // 255 = unknown
        uint2 e01 = *(const uint2*)(ebw + (size_t)j * ECAP);     // slots 0,1
        sm.sc.pr[j] = (e01.x & 0xFFFFu) | (e01.y << 16);
    }
    __syncthreads();
    if (tid < 64) {
        int lane = tid;
        int kc = 0;
        for (int c0 = 0; c0 < NCHUNK; ++c0) {
            int base = c0 * 64;
            int j = base + lane;
            bool valid = j < PRE;
            uint64_t word = __ballot(valid);
            int cv = valid ? (int)sm.sc.cl[j] : 0;
            uint32_t prv = sm.sc.pr[j];
            uint4 ev = make_uint4(0u, 0u, 0u, 0u);
            bool manym = (cv >= 3 && cv <= ECAP);
            if (__ballot(manym)) {
                if (manym) {
                    const uint4* e128 = (const uint4*)(ebw + (size_t)j * ECAP);
                    uint4 lo = e128[0], hi = e128[1];
                    ev.x = (lo.x & 0xFFFFu) | (lo.y << 16);
                    ev.y = (lo.z & 0xFFFFu) | (lo.w << 16);
                    ev.z = (hi.x & 0xFFFFu) | (hi.y << 16);
                    ev.w = (hi.z & 0xFFFFu) | (hi.w << 16);
                }
            }
            bool same = false, supB = false;
            bool hard = valid && (cv > ECAP);
            if (valid && cv > 0 && cv <= ECAP) {
                if (cv <= 2) {
                    int p0 = (int)(prv & 0xFFFFu);
                    int p1 = (int)(prv >> 16);
                    bool s1 = (cv == 2) && (p1 >= base);
                    same = (p0 >= base) || s1;
                    if (!same) {
                        supB = ((sm.sc.km[p0 >> 6] >> (p0 & 63)) & 1ull) != 0ull;
                        if (!supB && cv == 2)
                            supB = ((sm.sc.km[p1 >> 6] >> (p1 & 63)) & 1ull) != 0ull;
                    }
                } else {
                    int es[8] = { (int)(ev.x & 0xFFFFu), (int)(ev.x >> 16),
                                  (int)(ev.y & 0xFFFFu), (int)(ev.y >> 16),
                                  (int)(ev.z & 0xFFFFu), (int)(ev.z >> 16),
                                  (int)(ev.w & 0xFFFFu), (int)(ev.w >> 16) };
                    #pragma unroll
                    for (int k = 0; k < 8; ++k)
                        if (k < cv) same = same || (es[k] >= base);
                    if (!same) {
                        #pragma unroll
                        for (int k = 0; k < 8; ++k)
                            if (k < cv && !supB)
                                supB = ((sm.sc.km[es[k] >> 6] >> (es[k] & 63)) & 1ull) != 0ull;
                    }
                }
            }
            word &= ~__ballot(supB);
            uint64_t fix = __ballot(same || hard);
            while (fix) {
                int p = __ffsll((unsigned long long)fix) - 1;
                fix &= fix - 1;
                int jp = base + p;
                int cvp = __shfl(cv, p);
                bool sup = false;
                if (cvp <= ECAP) {
                    uint32_t prp = (uint32_t)__shfl((int)prv, p);
                    uint32_t evx = (uint32_t)__shfl((int)ev.x, p);
                    uint32_t evy = (uint32_t)__shfl((int)ev.y, p);
                    uint32_t evz = (uint32_t)__shfl((int)ev.z, p);
                    uint32_t evw = (uint32_t)__shfl((int)ev.w, p);
                    int es[8];
                    if (cvp <= 2) {
                        es[0] = (int)(prp & 0xFFFFu); es[1] = (int)(prp >> 16);
                        es[2] = es[3] = es[4] = es[5] = es[6] = es[7] = 0;
                    } else {
                        es[0] = (int)(evx & 0xFFFFu); es[1] = (int)(evx >> 16);
                        es[2] = (int)(evy & 0xFFFFu); es[3] = (int)(evy >> 16);
                        es[4] = (int)(evz & 0xFFFFu); es[5] = (int)(evz >> 16);
                        es[6] = (int)(evw & 0xFFFFu); es[7] = (int)(evw >> 16);
                    }
                    #pragma unroll
                    for (int k = 0; k < 8; ++k) {
                        if (k < cvp && !sup) {
                            int e = es[k];
                            bool kept = (e >= base)
                                ? (((word >> (e - base)) & 1ull) != 0ull)
                                : (((sm.sc.km[e >> 6] >> (e & 63)) & 1ull) != 0ull);
                            sup = sup || kept;
                        }
                    }
                } else {
                    float4 J = bx[jp];
                    bool any = false;
                    for (int t2 = lane; t2 < kc; t2 += 64)
                        if (iou_of(bx[sm.sc.list[t2]], J) > NMS_THR) any = true;
                    if (lane < p && ((word >> lane) & 1ull))
                        if (iou_of(bx[base + lane], J) > NMS_THR) any = true;
                    sup = (__ballot(any) != 0ull);
                }
                if (sup) word &= ~(1ull << p);
            }
            sm.sc.km[c0] = word;
            int pos = kc + __popcll(word & ((1ull << lane) - 1ull));
            if (((word >> lane) & 1ull) && pos < OUT_CNT) sm.sc.list[pos] = (uint16_t)j;
            kc += __popcll(word);
            if (kc >= OUT_CNT) { kc = OUT_CNT; break; }
        }
        if (lane == 0) sm.sc.kcs = kc;
    }
    __syncthreads();
    int kc = sm.sc.kcs;
    float4* ob = (float4*)(out) + (size_t)b * OUT_CNT;
    for (int r = tid; r < OUT_CNT; r += 256) {
        float4 o = make_float4(0.f, 0.f, 0.f, 0.f);
        if (r < kc) o = bx[sm.sc.list[r]];
        ob[r] = o;
    }
}

extern "C" void kernel_launch(void* const* d_in, const int* in_sizes, int n_in,
                              void* d_out, int out_size, void* d_ws, size_t ws_size,
                              hipStream_t stream) {
    const float* probs   = (const float*)d_in[0];
    const float* rpnbbox = (const float*)d_in[1];
    const float* anchors = (const float*)d_in[2];
    float* out = (float*)d_out;
    char* ws = (char*)d_ws;

    uint32_t* pref  = (uint32_t*)(ws + OFF_PREF);
    uint32_t* lcnts = (uint32_t*)(ws + OFF_LCNTS);
    uint64_t* slab  = (uint64_t*)(ws + OFF_SLAB);
    uint32_t* cnt   = (uint32_t*)(ws + OFF_CNT);
    uint32_t* done2 = (uint32_t*)(ws + OFF_DONE2);
    float*    boxes = (float*)(ws + OFF_BOXES);
    uint32_t* edges = (uint32_t*)(ws + OFF_EDGES);

    k_pass1<<<dim3(NSUB, NBATCH), 256, 0, stream>>>(probs, pref, lcnts, slab,
                                                    (uint4*)(ws + OFF_CNT));
    k_binsel<<<dim3(128, NBATCH), 256, 0, stream>>>(probs, pref, lcnts, slab,
                                                    rpnbbox, anchors, boxes);
    k_edgescan<<<dim3(NTPE, NBATCH), 256, 0, stream>>>(boxes, cnt, edges, done2, out);
}

// Round 15
// 81.168 us; speedup vs baseline: 1.4463x; 1.0825x over previous
//
#include <hip/hip_runtime.h>
#include <stdint.h>

#define NBATCH   8
#define NA       261888
#define PRE      6000
#define PREP     6016
#define NCHUNK   94
#define OUT_CNT  2000
#define NMS_THR  0.7f
#define NBINS    4096
#define NHB      160      // histogrammed bins: [T0S, 4096)
#define T0S      3936     // static pre-threshold bin: E[cands]=10230 >> 6000
#define NSUB     64       // pass1 blocks per batch
#define LCAP     512      // per-block candidate segment (E=160, 28 sigma headroom)
#define ECAP     8
#define SEGCAP   2048
#define J0       3072     // edges computed only for j < J0; scan falls back past it
#define NJT      12       // J0 / 256
#define NTPE     78       // NJT*(NJT+1)/2 tile-pairs

// workspace layout (bytes) — all state (re)written every call; poison-safe
#define OFF_PREF     0ull                      // 8*64*161*4 = 329728
#define OFF_LCNTS    329728ull                 // 2048 -> 331776
#define OFF_SLAB     331776ull                 // 8*64*512*8 = 2097152 -> 2428928
#define OFF_CNT      2428928ull                // 8*6016*4 = 192512 -> 2621440
#define OFF_DONE2    2621440ull                // 8 * 64B = 512 (zeroed with cnt) -> 2621952
#define NZ4          12064                     // (192512+512)/16 uint4s
#define OFF_BOXES    2621952ull                // 8*6016*16 = 770048 -> 3392000
#define OFF_EDGES    3392000ull                // 8*6016*8*4 = 1540096 -> 4932096

__device__ __forceinline__ int score_bin(float s) {
    int b = (int)(s * 4096.0f);          // *4096 exact (pow2) -> monotone
    return min(max(b, 0), NBINS - 1);
}

__device__ __forceinline__ float iou_of(float4 A, float4 Bv) {
    float ai = (A.z - A.x) * (A.w - A.y);
    float aj = (Bv.z - Bv.x) * (Bv.w - Bv.y);
    float yy1 = fmaxf(A.x, Bv.x), xx1 = fmaxf(A.y, Bv.y);
    float yy2 = fminf(A.z, Bv.z), xx2 = fminf(A.w, Bv.w);
    float inter = fmaxf(yy2 - yy1, 0.f) * fmaxf(xx2 - xx1, 0.f);
    float uni = (ai + aj) - inter;
    return (uni > 0.f) ? inter / uni : 0.f;
}

__device__ __forceinline__ void box_transform(uint64_t keyv, const float4* an4,
                                              const float4* bb4, float4* bx, uint32_t pos) {
    uint32_t aidx = (uint32_t)(keyv & 0xFFFFFFFFu);
    float4 a = an4[aidx];
    float4 d = bb4[aidx];
    float dy = d.x * 0.1f, dx = d.y * 0.1f, dh = d.z * 0.2f, dw = d.w * 0.2f;
    float h = a.z - a.x, w = a.w - a.y;
    float cy = a.x + 0.5f * h;  cy = cy + dy * h;
    float cx = a.y + 0.5f * w;  cx = cx + dx * w;
    h = h * expf(dh);
    w = w * expf(dw);
    float y1 = cy - 0.5f * h, x1 = cx - 0.5f * w;
    float y2 = y1 + h, x2 = x1 + w;
    float4 o;
    o.x = fminf(fmaxf(y1, 0.f), 1.f);
    o.y = fminf(fmaxf(x1, 0.f), 1.f);
    o.z = fminf(fmaxf(y2, 0.f), 1.f);
    o.w = fminf(fmaxf(x2, 0.f), 1.f);
    bx[pos] = o;
}

// ---------------- K1: stream probs -> bin-grouped per-block slabs + prefix ----------------
// Also zeroes cnt+done2 (consumed by K3, two kernel-boundaries later).
__global__ __launch_bounds__(256) void k_pass1(
        const float* __restrict__ probs, uint32_t* __restrict__ pref,
        uint32_t* __restrict__ lcnts, uint64_t* __restrict__ slab,
        uint4* __restrict__ zcnt) {
    __shared__ uint32_t h[NHB];
    __shared__ uint32_t lp[NHB + 1];
    __shared__ uint64_t lkey[LCAP];
    __shared__ uint32_t lcnt;
    int b = blockIdx.y, sub = blockIdx.x, tid = threadIdx.x;
    int blk = b * NSUB + sub;
    {   // zero cnt+done2 (12064 uint4 over 512 blocks x 24)
        int zi = blk * 24 + tid;
        if (tid < 24 && zi < NZ4) zcnt[zi] = make_uint4(0u, 0u, 0u, 0u);
    }
    if (tid < NHB) h[tid] = 0;
    if (tid == 0) lcnt = 0;
    __syncthreads();
    const float4* p4 = (const float4*)(probs + (size_t)b * NA * 2);
    const int total = NA / 2;
    for (int q = sub * 256 + tid; q < total; q += NSUB * 256) {
        float4 v = p4[q];
        #pragma unroll
        for (int k = 0; k < 2; ++k) {
            float s = k ? v.w : v.y;
            int bin = score_bin(s);
            if (bin >= T0S) {                        // ~0.04% of anchors
                atomicAdd(&h[bin - T0S], 1u);
                uint32_t p = atomicAdd(&lcnt, 1u);
                if (p < LCAP) {
                    uint32_t sb = __float_as_uint(s);
                    lkey[p] = ((uint64_t)(~sb) << 32) | (uint32_t)(2 * q + k);
                }
            }
        }
    }
    __syncthreads();
    if (tid == 0) {                                  // ascending-bin local prefix
        uint32_t a = 0;
        for (int i = 0; i < NHB; ++i) { lp[i] = a; a += h[i]; }
        lp[NHB] = a;
    }
    __syncthreads();
    uint32_t* gp = pref + (size_t)blk * (NHB + 1);
    if (tid <= NHB) gp[tid] = lp[tid];
    if (tid == 0) lcnts[blk] = lcnt;                 // raw count (overflow detect)
    if (tid < NHB) h[tid] = lp[tid];                 // reuse as running counters
    __syncthreads();
    uint64_t* gs = slab + (size_t)blk * LCAP;
    uint32_t n = min(lcnt, (uint32_t)LCAP);
    for (uint32_t i = tid; i < n; i += 256) {
        uint64_t k = lkey[i];
        float s = __uint_as_float(~(uint32_t)(k >> 32));
        int bi = score_bin(s) - T0S;
        uint32_t pos = atomicAdd(&h[bi], 1u);
        if (pos < LCAP) gs[pos] = k;
    }
}

// ---------------- K2: per-block select recompute + bin collect + sort + transform ----------
__global__ __launch_bounds__(256) void k_binsel(
        const float* __restrict__ probs, const uint32_t* __restrict__ pref,
        const uint32_t* __restrict__ lcnts, const uint64_t* __restrict__ slab,
        const float* __restrict__ rpn_bbox, const float* __restrict__ anchors,
        float* __restrict__ boxes) {
    __shared__ uint32_t hS[NHB];
    __shared__ uint32_t cS[NHB + 1];
    __shared__ uint64_t key[SEGCAP];     // 16 KB
    __shared__ uint32_t hfull[NBINS];    // 16 KB (fallback only)
    __shared__ int Tsh;
    __shared__ uint32_t flag, ccS, baseS;
    int b = blockIdx.y, g = blockIdx.x, tid = threadIdx.x;
    const uint32_t* pb = pref + (size_t)b * NSUB * (NHB + 1);
    if (tid == 0) flag = 0;
    __syncthreads();
    if (tid < NHB) {
        uint32_t s = 0;
        for (int sub = 0; sub < NSUB; ++sub) {
            const uint32_t* pp = pb + (size_t)sub * (NHB + 1);
            s += pp[tid + 1] - pp[tid];
        }
        hS[tid] = s;
    }
    if (tid < NSUB && lcnts[b * NSUB + tid] > LCAP) atomicOr(&flag, 1u);
    __syncthreads();
    if (tid == 0) {
        uint32_t acc = 0;
        cS[NHB] = 0;
        int T = -1;
        for (int i = NHB - 1; i >= 0; --i) {
            acc += hS[i];
            cS[i] = acc;
            if (T < 0 && acc >= PRE) T = T0S + i;
        }
        Tsh = T;
    }
    __syncthreads();
    int T = Tsh;
    const float4* an4 = (const float4*)(anchors + (size_t)b * NA * 4);
    const float4* bb4 = (const float4*)(rpn_bbox + (size_t)b * NA * 4);
    float4* bx = (float4*)(boxes) + (size_t)b * PREP;

    if (flag != 0 || T < 0) {
        // ---- exact fallback (never taken): block g==0 recomputes everything ----
        if (g != 0) return;
        const float4* p4 = (const float4*)(probs + (size_t)b * NA * 2);
        for (int i = tid; i < NBINS; i += 256) hfull[i] = 0;
        __syncthreads();
        for (int q = tid; q < NA / 2; q += 256) {
            float4 v = p4[q];
            atomicAdd(&hfull[score_bin(v.y)], 1u);
            atomicAdd(&hfull[score_bin(v.w)], 1u);
        }
        __syncthreads();
        if (tid == 0) baseS = 0;
        __syncthreads();
        for (int bin = NBINS - 1; bin >= 0; --bin) {
            uint32_t n = hfull[bin];
            uint32_t base = baseS;
            if (base >= PRE) break;
            if (n) {
                int P = 1; while (P < (int)n) P <<= 1;
                if (P > SEGCAP) P = SEGCAP;
                for (int i = tid; i < P; i += 256) key[i] = ~0ull;
                if (tid == 0) ccS = 0;
                __syncthreads();
                for (int q = tid; q < NA / 2; q += 256) {
                    float4 v = p4[q];
                    #pragma unroll
                    for (int k = 0; k < 2; ++k) {
                        float s = k ? v.w : v.y;
                        if (score_bin(s) == bin) {
                            uint32_t pos = atomicAdd(&ccS, 1u);
                            if (pos < (uint32_t)P) {
                                uint32_t sb2 = __float_as_uint(s);
                                key[pos] = ((uint64_t)(~sb2) << 32) | (uint32_t)(2 * q + k);
                            }
                        }
                    }
                }
                __syncthreads();
                for (int kk = 2; kk <= P; kk <<= 1) {
                    for (int j = kk >> 1; j > 0; j >>= 1) {
                        for (int i = tid; i < P; i += 256) {
                            int ixj = i ^ j;
                            if (ixj > i) {
                                uint64_t a = key[i], c = key[ixj];
                                bool up = ((i & kk) == 0);
                                if ((a > c) == up) { key[i] = c; key[ixj] = a; }
                            }
                        }
                        __syncthreads();
                    }
                }
                for (int r = tid; r < (int)n; r += 256) {
                    uint32_t pos = base + (uint32_t)r;
                    if (pos < PRE && r < SEGCAP) box_transform(key[r], an4, bb4, bx, pos);
                }
                __syncthreads();
            }
            if (tid == 0) baseS = base + n;
            __syncthreads();
        }
        return;
    }

    // ---- normal path: bins T+g, T+g+128, ... ----
    for (int bin = T + g; bin < NBINS; bin += 128) {
        int m = bin - T0S;                   // >= 0 since T >= T0S here
        int n = (int)hS[m];
        if (n == 0) continue;
        uint32_t base = cS[m + 1];           // count strictly above this bin
        if (base >= PRE) continue;
        if (n > SEGCAP) n = SEGCAP;
        int P = 1; while (P < n) P <<= 1;
        for (int i = tid; i < P; i += 256) key[i] = ~0ull;
        if (tid == 0) ccS = 0;
        __syncthreads();
        if (tid < NSUB) {                    // collect this bin's entries from all slabs
            const uint32_t* pp = pb + (size_t)tid * (NHB + 1);
            uint32_t s0 = pp[m], s1 = pp[m + 1];
            const uint64_t* gs = slab + (size_t)(b * NSUB + tid) * LCAP;
            for (uint32_t i = s0; i < s1; ++i) {
                uint32_t pos = atomicAdd(&ccS, 1u);
                if (pos < (uint32_t)P) key[pos] = gs[i];
            }
        }
        __syncthreads();
        for (int kk = 2; kk <= P; kk <<= 1) {
            for (int j = kk >> 1; j > 0; j >>= 1) {
                for (int i = tid; i < P; i += 256) {
                    int ixj = i ^ j;
                    if (ixj > i) {
                        uint64_t a = key[i], c = key[ixj];
                        bool up = ((i & kk) == 0);
                        if ((a > c) == up) { key[i] = c; key[ixj] = a; }
                    }
                }
                __syncthreads();
            }
        }
        for (int r = tid; r < n; r += 256) {
            uint32_t pos = base + (uint32_t)r;
            if (pos < PRE) box_transform(key[r], an4, bb4, bx, pos);
        }
        __syncthreads();
    }
}

// ---------------- K3: edges (atomic stores) + last-block-per-batch scan (no fences) --------
struct ScanSh {
    uint8_t  cl[PREP];
    uint32_t pr[PREP];
    uint64_t km[NCHUNK];
    uint16_t list[OUT_CNT];
    int      kcs;
};
union EsSh {
    float4 sb[256];
    ScanSh sc;
};

__global__ __launch_bounds__(256) void k_edgescan(
        const float* __restrict__ boxes, uint32_t* __restrict__ cnt,
        uint32_t* __restrict__ edges, uint32_t* __restrict__ done2,
        float* __restrict__ out) {
    __shared__ EsSh sm;
    __shared__ uint32_t rankS;
    int b = blockIdx.y;
    int t = blockIdx.x;
    int tid = threadIdx.x;
    int ti = 0, rem = t;
    while (rem >= NJT - ti) { rem -= NJT - ti; ++ti; }
    int tj = ti + rem;                       // ti <= tj < NJT
    const float4* bx = (const float4*)(boxes) + (size_t)b * PREP;
    sm.sb[tid] = bx[ti * 256 + tid];
    __syncthreads();
    {
        int gj = tj * 256 + tid;
        float4 Jb = bx[gj];
        float jy1 = Jb.x, jx1 = Jb.y, jy2 = Jb.z, jx2 = Jb.w;
        float aj = (jy2 - jy1) * (jx2 - jx1);
        float thr = 0.6f * aj;
        bool diag = (ti == tj);
        uint32_t* cb = cnt + (size_t)b * PREP;
        uint32_t* eb = edges + (size_t)b * PREP * ECAP;
        int gibase = ti * 256;
        #pragma unroll 4
        for (int it = 0; it < 256; ++it) {
            float4 I = sm.sb[it];            // broadcast, conflict-free
            float yy1 = fmaxf(jy1, I.x), xx1 = fmaxf(jx1, I.y);
            float yy2 = fminf(jy2, I.z), xx2 = fminf(jx2, I.w);
            float ih = fmaxf(yy2 - yy1, 0.f), iw = fmaxf(xx2 - xx1, 0.f);
            float inter = ih * iw;
            if (inter > thr) {               // rare path
                int gi = gibase + it;
                if (!diag || gi < gj) {
                    float ai = (I.z - I.x) * (I.w - I.y);
                    float uni = (ai + aj) - inter;   // reference op order
                    float iou = inter / uni;
                    if (iou > NMS_THR) {
                        uint32_t slot = atomicAdd(&cb[gj], 1u);
                        if (slot < ECAP)
                            atomicExch(&eb[(size_t)gj * ECAP + slot], (uint32_t)gi);
                    }
                }
            }
        }
    }
    __syncthreads();                         // vmcnt(0): all this block's atomics completed
    if (tid == 0) rankS = atomicAdd(&done2[b * 16], 1u);   // padded: one line per batch
    __syncthreads();
    if (rankS != NTPE - 1) return;
    // last block of batch: peers' cnt/edge atomics are at the coherence point;
    // this XCD's caches never cached those lines this kernel -> plain loads see them.

    const uint32_t* cb = cnt + (size_t)b * PREP;
    const uint32_t* ebw = edges + (size_t)b * PREP * ECAP;
    #pragma unroll 4
    for (int j = tid; j < PREP; j += 256) {
        if (j < J0) {
            uint32_t c = cb[j];
            sm.sc.cl[j] = (uint8_t)(c > 255u ? 255u : c);
            uint2 e01 = *(const uint2*)(ebw + (size_t)j * ECAP);     // slots 0,1
            sm.sc.pr[j] = (e01.x & 0xFFFFu) | (e01.y << 16);
        } else {
            sm.sc.cl[j] = (uint8_t)255;      // unknown -> exact fallback path
            sm.sc.pr[j] = 0;
        }
    }
    __syncthreads();
    if (tid < 64) {
        int lane = tid;
        int kc = 0;
        for (int c0 = 0; c0 < NCHUNK; ++c0) {
            int base = c0 * 64;
            int j = base + lane;
            bool valid = j < PRE;
            uint64_t word = __ballot(valid);
            int cv = valid ? (int)sm.sc.cl[j] : 0;
            uint32_t prv = sm.sc.pr[j];
            uint4 ev = make_uint4(0u, 0u, 0u, 0u);
            bool manym = (cv >= 3 && cv <= ECAP);
            if (__ballot(manym)) {
                if (manym) {
                    const uint4* e128 = (const uint4*)(ebw + (size_t)j * ECAP);
                    uint4 lo = e128[0], hi = e128[1];
                    ev.x = (lo.x & 0xFFFFu) | (lo.y << 16);
                    ev.y = (lo.z & 0xFFFFu) | (lo.w << 16);
                    ev.z = (hi.x & 0xFFFFu) | (hi.y << 16);
                    ev.w = (hi.z & 0xFFFFu) | (hi.w << 16);
                }
            }
            bool same = false, supB = false;
            bool hard = valid && (cv > ECAP);
            if (valid && cv > 0 && cv <= ECAP) {
                if (cv <= 2) {
                    int p0 = (int)(prv & 0xFFFFu);
                    int p1 = (int)(prv >> 16);
                    bool s1 = (cv == 2) && (p1 >= base);
                    same = (p0 >= base) || s1;
                    if (!same) {
                        supB = ((sm.sc.km[p0 >> 6] >> (p0 & 63)) & 1ull) != 0ull;
                        if (!supB && cv == 2)
                            supB = ((sm.sc.km[p1 >> 6] >> (p1 & 63)) & 1ull) != 0ull;
                    }
                } else {
                    int es[8] = { (int)(ev.x & 0xFFFFu), (int)(ev.x >> 16),
                                  (int)(ev.y & 0xFFFFu), (int)(ev.y >> 16),
                                  (int)(ev.z & 0xFFFFu), (int)(ev.z >> 16),
                                  (int)(ev.w & 0xFFFFu), (int)(ev.w >> 16) };
                    #pragma unroll
                    for (int k = 0; k < 8; ++k)
                        if (k < cv) same = same || (es[k] >= base);
                    if (!same) {
                        #pragma unroll
                        for (int k = 0; k < 8; ++k)
                            if (k < cv && !supB)
                                supB = ((sm.sc.km[es[k] >> 6] >> (es[k] & 63)) & 1ull) != 0ull;
                    }
                }
            }
            word &= ~__ballot(supB);
            uint64_t fix = __ballot(same || hard);
            while (fix) {
                int p = __ffsll((unsigned long long)fix) - 1;
                fix &= fix - 1;
                int jp = base + p;
                int cvp = __shfl(cv, p);
                bool sup = false;
                if (cvp <= ECAP) {
                    uint32_t prp = (uint32_t)__shfl((int)prv, p);
                    uint32_t evx = (uint32_t)__shfl((int)ev.x, p);
                    uint32_t evy = (uint32_t)__shfl((int)ev.y, p);
                    uint32_t evz = (uint32_t)__shfl((int)ev.z, p);
                    uint32_t evw = (uint32_t)__shfl((int)ev.w, p);
                    int es[8];
                    if (cvp <= 2) {
                        es[0] = (int)(prp & 0xFFFFu); es[1] = (int)(prp >> 16);
                        es[2] = es[3] = es[4] = es[5] = es[6] = es[7] = 0;
                    } else {
                        es[0] = (int)(evx & 0xFFFFu); es[1] = (int)(evx >> 16);
                        es[2] = (int)(evy & 0xFFFFu); es[3] = (int)(evy >> 16);
                        es[4] = (int)(evz & 0xFFFFu); es[5] = (int)(evz >> 16);
                        es[6] = (int)(evw & 0xFFFFu); es[7] = (int)(evw >> 16);
                    }
                    #pragma unroll
                    for (int k = 0; k < 8; ++k) {
                        if (k < cvp && !sup) {
                            int e = es[k];
                            bool kept = (e >= base)
                                ? (((word >> (e - base)) & 1ull) != 0ull)
                                : (((sm.sc.km[e >> 6] >> (e & 63)) & 1ull) != 0ull);
                            sup = sup || kept;
                        }
                    }
                } else {
                    float4 J = bx[jp];
                    bool any = false;
                    for (int t2 = lane; t2 < kc; t2 += 64)
                        if (iou_of(bx[sm.sc.list[t2]], J) > NMS_THR) any = true;
                    if (lane < p && ((word >> lane) & 1ull))
                        if (iou_of(bx[base + lane], J) > NMS_THR) any = true;
                    sup = (__ballot(any) != 0ull);
                }
                if (sup) word &= ~(1ull << p);
            }
            sm.sc.km[c0] = word;
            int pos = kc + __popcll(word & ((1ull << lane) - 1ull));
            if (((word >> lane) & 1ull) && pos < OUT_CNT) sm.sc.list[pos] = (uint16_t)j;
            kc += __popcll(word);
            if (kc >= OUT_CNT) { kc = OUT_CNT; break; }
        }
        if (lane == 0) sm.sc.kcs = kc;
    }
    __syncthreads();
    int kc = sm.sc.kcs;
    float4* ob = (float4*)(out) + (size_t)b * OUT_CNT;
    for (int r = tid; r < OUT_CNT; r += 256) {
        float4 o = make_float4(0.f, 0.f, 0.f, 0.f);
        if (r < kc) o = bx[sm.sc.list[r]];
        ob[r] = o;
    }
}

extern "C" void kernel_launch(void* const* d_in, const int* in_sizes, int n_in,
                              void* d_out, int out_size, void* d_ws, size_t ws_size,
                              hipStream_t stream) {
    const float* probs   = (const float*)d_in[0];
    const float* rpnbbox = (const float*)d_in[1];
    const float* anchors = (const float*)d_in[2];
    float* out = (float*)d_out;
    char* ws = (char*)d_ws;

    uint32_t* pref  = (uint32_t*)(ws + OFF_PREF);
    uint32_t* lcnts = (uint32_t*)(ws + OFF_LCNTS);
    uint64_t* slab  = (uint64_t*)(ws + OFF_SLAB);
    uint32_t* cnt   = (uint32_t*)(ws + OFF_CNT);
    uint32_t* done2 = (uint32_t*)(ws + OFF_DONE2);
    float*    boxes = (float*)(ws + OFF_BOXES);
    uint32_t* edges = (uint32_t*)(ws + OFF_EDGES);

    k_pass1<<<dim3(NSUB, NBATCH), 256, 0, stream>>>(probs, pref, lcnts, slab,
                                                    (uint4*)(ws + OFF_CNT));
    k_binsel<<<dim3(128, NBATCH), 256, 0, stream>>>(probs, pref, lcnts, slab,
                                                    rpnbbox, anchors, boxes);
    k_edgescan<<<dim3(NTPE, NBATCH), 256, 0, stream>>>(boxes, cnt, edges, done2, out);
}

// Round 16
// 77.588 us; speedup vs baseline: 1.5130x; 1.0461x over previous
//
#include <hip/hip_runtime.h>
#include <stdint.h>

#define NBATCH   8
#define NA       261888
#define PRE      6000
#define PREP     6016
#define NCHUNK   94
#define OUT_CNT  2000
#define NMS_THR  0.7f
#define NBINS    4096
#define NHB      160      // histogrammed bins: [T0S, 4096)
#define T0S      3936     // static pre-threshold bin: E[cands]=10230 >> 6000
#define NSUB     64       // pass1 blocks per batch
#define LCAP     512      // per-block candidate segment (E=160, 28 sigma headroom)
#define ECAP     8
#define SEGCAP   2048
#define J0       2560     // edges computed only for j < J0; scan falls back past it
                          // (scan stop j* ~= 2000/(1-0.08) ~= 2180, margin ~380)
#define NJT      10       // J0 / 256
#define NTPE     55       // NJT*(NJT+1)/2 tile-pairs

// workspace layout (bytes) — all state (re)written every call; poison-safe
#define OFF_PREF     0ull                      // 8*64*161*4 = 329728
#define OFF_LCNTS    329728ull                 // 2048 -> 331776
#define OFF_SLAB     331776ull                 // 8*64*512*8 = 2097152 -> 2428928
#define OFF_CNT      2428928ull                // 8*6016*4 = 192512 -> 2621440
#define OFF_DONE2    2621440ull                // 8 * 64B = 512 (zeroed with cnt) -> 2621952
#define NZ4          12064                     // (192512+512)/16 uint4s
#define OFF_BOXES    2621952ull                // 8*6016*16 = 770048 -> 3392000
#define OFF_EDGES    3392000ull                // 8*6016*8*4 = 1540096 -> 4932096

__device__ __forceinline__ int score_bin(float s) {
    int b = (int)(s * 4096.0f);          // *4096 exact (pow2) -> monotone
    return min(max(b, 0), NBINS - 1);
}

__device__ __forceinline__ float iou_of(float4 A, float4 Bv) {
    float ai = (A.z - A.x) * (A.w - A.y);
    float aj = (Bv.z - Bv.x) * (Bv.w - Bv.y);
    float yy1 = fmaxf(A.x, Bv.x), xx1 = fmaxf(A.y, Bv.y);
    float yy2 = fminf(A.z, Bv.z), xx2 = fminf(A.w, Bv.w);
    float inter = fmaxf(yy2 - yy1, 0.f) * fmaxf(xx2 - xx1, 0.f);
    float uni = (ai + aj) - inter;
    return (uni > 0.f) ? inter / uni : 0.f;
}

__device__ __forceinline__ void box_transform(uint64_t keyv, const float4* an4,
                                              const float4* bb4, float4* bx, uint32_t pos) {
    uint32_t aidx = (uint32_t)(keyv & 0xFFFFFFFFu);
    float4 a = an4[aidx];
    float4 d = bb4[aidx];
    float dy = d.x * 0.1f, dx = d.y * 0.1f, dh = d.z * 0.2f, dw = d.w * 0.2f;
    float h = a.z - a.x, w = a.w - a.y;
    float cy = a.x + 0.5f * h;  cy = cy + dy * h;
    float cx = a.y + 0.5f * w;  cx = cx + dx * w;
    h = h * expf(dh);
    w = w * expf(dw);
    float y1 = cy - 0.5f * h, x1 = cx - 0.5f * w;
    float y2 = y1 + h, x2 = x1 + w;
    float4 o;
    o.x = fminf(fmaxf(y1, 0.f), 1.f);
    o.y = fminf(fmaxf(x1, 0.f), 1.f);
    o.z = fminf(fmaxf(y2, 0.f), 1.f);
    o.w = fminf(fmaxf(x2, 0.f), 1.f);
    bx[pos] = o;
}

// ---------------- K1: stream probs -> bin-grouped per-block slabs + prefix ----------------
// Also zeroes cnt+done2 (consumed by K3, two kernel-boundaries later).
__global__ __launch_bounds__(256) void k_pass1(
        const float* __restrict__ probs, uint32_t* __restrict__ pref,
        uint32_t* __restrict__ lcnts, uint64_t* __restrict__ slab,
        uint4* __restrict__ zcnt) {
    __shared__ uint32_t h[NHB];
    __shared__ uint32_t lp[NHB + 1];
    __shared__ uint64_t lkey[LCAP];
    __shared__ uint32_t lcnt;
    int b = blockIdx.y, sub = blockIdx.x, tid = threadIdx.x;
    int blk = b * NSUB + sub;
    {   // zero cnt+done2 (12064 uint4 over 512 blocks x 24)
        int zi = blk * 24 + tid;
        if (tid < 24 && zi < NZ4) zcnt[zi] = make_uint4(0u, 0u, 0u, 0u);
    }
    if (tid < NHB) h[tid] = 0;
    if (tid == 0) lcnt = 0;
    __syncthreads();
    const float4* p4 = (const float4*)(probs + (size_t)b * NA * 2);
    const int total = NA / 2;
    for (int q = sub * 256 + tid; q < total; q += NSUB * 256) {
        float4 v = p4[q];
        #pragma unroll
        for (int k = 0; k < 2; ++k) {
            float s = k ? v.w : v.y;
            int bin = score_bin(s);
            if (bin >= T0S) {                        // ~0.04% of anchors
                atomicAdd(&h[bin - T0S], 1u);
                uint32_t p = atomicAdd(&lcnt, 1u);
                if (p < LCAP) {
                    uint32_t sb = __float_as_uint(s);
                    lkey[p] = ((uint64_t)(~sb) << 32) | (uint32_t)(2 * q + k);
                }
            }
        }
    }
    __syncthreads();
    if (tid == 0) {                                  // ascending-bin local prefix
        uint32_t a = 0;
        for (int i = 0; i < NHB; ++i) { lp[i] = a; a += h[i]; }
        lp[NHB] = a;
    }
    __syncthreads();
    uint32_t* gp = pref + (size_t)blk * (NHB + 1);
    if (tid <= NHB) gp[tid] = lp[tid];
    if (tid == 0) lcnts[blk] = lcnt;                 // raw count (overflow detect)
    if (tid < NHB) h[tid] = lp[tid];                 // reuse as running counters
    __syncthreads();
    uint64_t* gs = slab + (size_t)blk * LCAP;
    uint32_t n = min(lcnt, (uint32_t)LCAP);
    for (uint32_t i = tid; i < n; i += 256) {
        uint64_t k = lkey[i];
        float s = __uint_as_float(~(uint32_t)(k >> 32));
        int bi = score_bin(s) - T0S;
        uint32_t pos = atomicAdd(&h[bi], 1u);
        if (pos < LCAP) gs[pos] = k;
    }
}

// ---------------- K2: per-block select recompute + bin collect + sort + transform ----------
__global__ __launch_bounds__(256) void k_binsel(
        const float* __restrict__ probs, const uint32_t* __restrict__ pref,
        const uint32_t* __restrict__ lcnts, const uint64_t* __restrict__ slab,
        const float* __restrict__ rpn_bbox, const float* __restrict__ anchors,
        float* __restrict__ boxes) {
    __shared__ uint32_t hS[NHB];
    __shared__ uint32_t cS[NHB + 1];
    __shared__ uint64_t key[SEGCAP];     // 16 KB
    __shared__ uint32_t hfull[NBINS];    // 16 KB (fallback only)
    __shared__ int Tsh;
    __shared__ uint32_t flag, ccS, baseS;
    int b = blockIdx.y, g = blockIdx.x, tid = threadIdx.x;
    const uint32_t* pb = pref + (size_t)b * NSUB * (NHB + 1);
    if (tid == 0) flag = 0;
    __syncthreads();
    if (tid < NHB) {
        uint32_t s = 0;
        for (int sub = 0; sub < NSUB; ++sub) {
            const uint32_t* pp = pb + (size_t)sub * (NHB + 1);
            s += pp[tid + 1] - pp[tid];
        }
        hS[tid] = s;
    }
    if (tid < NSUB && lcnts[b * NSUB + tid] > LCAP) atomicOr(&flag, 1u);
    __syncthreads();
    if (tid == 0) {
        uint32_t acc = 0;
        cS[NHB] = 0;
        int T = -1;
        for (int i = NHB - 1; i >= 0; --i) {
            acc += hS[i];
            cS[i] = acc;
            if (T < 0 && acc >= PRE) T = T0S + i;
        }
        Tsh = T;
    }
    __syncthreads();
    int T = Tsh;
    const float4* an4 = (const float4*)(anchors + (size_t)b * NA * 4);
    const float4* bb4 = (const float4*)(rpn_bbox + (size_t)b * NA * 4);
    float4* bx = (float4*)(boxes) + (size_t)b * PREP;

    if (flag != 0 || T < 0) {
        // ---- exact fallback (never taken): block g==0 recomputes everything ----
        if (g != 0) return;
        const float4* p4 = (const float4*)(probs + (size_t)b * NA * 2);
        for (int i = tid; i < NBINS; i += 256) hfull[i] = 0;
        __syncthreads();
        for (int q = tid; q < NA / 2; q += 256) {
            float4 v = p4[q];
            atomicAdd(&hfull[score_bin(v.y)], 1u);
            atomicAdd(&hfull[score_bin(v.w)], 1u);
        }
        __syncthreads();
        if (tid == 0) baseS = 0;
        __syncthreads();
        for (int bin = NBINS - 1; bin >= 0; --bin) {
            uint32_t n = hfull[bin];
            uint32_t base = baseS;
            if (base >= PRE) break;
            if (n) {
                int P = 1; while (P < (int)n) P <<= 1;
                if (P > SEGCAP) P = SEGCAP;
                for (int i = tid; i < P; i += 256) key[i] = ~0ull;
                if (tid == 0) ccS = 0;
                __syncthreads();
                for (int q = tid; q < NA / 2; q += 256) {
                    float4 v = p4[q];
                    #pragma unroll
                    for (int k = 0; k < 2; ++k) {
                        float s = k ? v.w : v.y;
                        if (score_bin(s) == bin) {
                            uint32_t pos = atomicAdd(&ccS, 1u);
                            if (pos < (uint32_t)P) {
                                uint32_t sb2 = __float_as_uint(s);
                                key[pos] = ((uint64_t)(~sb2) << 32) | (uint32_t)(2 * q + k);
                            }
                        }
                    }
                }
                __syncthreads();
                for (int kk = 2; kk <= P; kk <<= 1) {
                    for (int j = kk >> 1; j > 0; j >>= 1) {
                        for (int i = tid; i < P; i += 256) {
                            int ixj = i ^ j;
                            if (ixj > i) {
                                uint64_t a = key[i], c = key[ixj];
                                bool up = ((i & kk) == 0);
                                if ((a > c) == up) { key[i] = c; key[ixj] = a; }
                            }
                        }
                        __syncthreads();
                    }
                }
                for (int r = tid; r < (int)n; r += 256) {
                    uint32_t pos = base + (uint32_t)r;
                    if (pos < PRE && r < SEGCAP) box_transform(key[r], an4, bb4, bx, pos);
                }
                __syncthreads();
            }
            if (tid == 0) baseS = base + n;
            __syncthreads();
        }
        return;
    }

    // ---- normal path: bins T+g, T+g+128, ... ----
    for (int bin = T + g; bin < NBINS; bin += 128) {
        int m = bin - T0S;                   // >= 0 since T >= T0S here
        int n = (int)hS[m];
        if (n == 0) continue;
        uint32_t base = cS[m + 1];           // count strictly above this bin
        if (base >= PRE) continue;
        if (n > SEGCAP) n = SEGCAP;
        int P = 1; while (P < n) P <<= 1;
        for (int i = tid; i < P; i += 256) key[i] = ~0ull;
        if (tid == 0) ccS = 0;
        __syncthreads();
        if (tid < NSUB) {                    // collect this bin's entries from all slabs
            const uint32_t* pp = pb + (size_t)tid * (NHB + 1);
            uint32_t s0 = pp[m], s1 = pp[m + 1];
            const uint64_t* gs = slab + (size_t)(b * NSUB + tid) * LCAP;
            for (uint32_t i = s0; i < s1; ++i) {
                uint32_t pos = atomicAdd(&ccS, 1u);
                if (pos < (uint32_t)P) key[pos] = gs[i];
            }
        }
        __syncthreads();
        for (int kk = 2; kk <= P; kk <<= 1) {
            for (int j = kk >> 1; j > 0; j >>= 1) {
                for (int i = tid; i < P; i += 256) {
                    int ixj = i ^ j;
                    if (ixj > i) {
                        uint64_t a = key[i], c = key[ixj];
                        bool up = ((i & kk) == 0);
                        if ((a > c) == up) { key[i] = c; key[ixj] = a; }
                    }
                }
                __syncthreads();
            }
        }
        for (int r = tid; r < n; r += 256) {
            uint32_t pos = base + (uint32_t)r;
            if (pos < PRE) box_transform(key[r], an4, bb4, bx, pos);
        }
        __syncthreads();
    }
}

// ---------------- K3: edges (atomic stores) + last-block-per-batch scan (no fences) --------
struct ScanSh {
    uint8_t  cl[PREP];
    uint32_t pr[PREP];
    uint64_t km[NCHUNK];
    uint16_t list[OUT_CNT];
    int      kcs;
};
union EsSh {
    float4 sb[256];
    ScanSh sc;
};

__global__ __launch_bounds__(256) void k_edgescan(
        const float* __restrict__ boxes, uint32_t* __restrict__ cnt,
        uint32_t* __restrict__ edges, uint32_t* __restrict__ done2,
        float* __restrict__ out) {
    __shared__ EsSh sm;
    __shared__ uint32_t rankS;
    int b = blockIdx.y;
    int t = blockIdx.x;
    int tid = threadIdx.x;
    int ti = 0, rem = t;
    while (rem >= NJT - ti) { rem -= NJT - ti; ++ti; }
    int tj = ti + rem;                       // ti <= tj < NJT
    const float4* bx = (const float4*)(boxes) + (size_t)b * PREP;
    sm.sb[tid] = bx[ti * 256 + tid];
    __syncthreads();
    {
        int gj = tj * 256 + tid;
        float4 Jb = bx[gj];
        float jy1 = Jb.x, jx1 = Jb.y, jy2 = Jb.z, jx2 = Jb.w;
        float aj = (jy2 - jy1) * (jx2 - jx1);
        float thr = 0.6f * aj;
        bool diag = (ti == tj);
        uint32_t* cb = cnt + (size_t)b * PREP;
        uint32_t* eb = edges + (size_t)b * PREP * ECAP;
        int gibase = ti * 256;
        #pragma unroll 4
        for (int it = 0; it < 256; ++it) {
            float4 I = sm.sb[it];            // broadcast, conflict-free
            float yy1 = fmaxf(jy1, I.x), xx1 = fmaxf(jx1, I.y);
            float yy2 = fminf(jy2, I.z), xx2 = fminf(jx2, I.w);
            float ih = fmaxf(yy2 - yy1, 0.f), iw = fmaxf(xx2 - xx1, 0.f);
            float inter = ih * iw;
            if (inter > thr) {               // rare path
                int gi = gibase + it;
                if (!diag || gi < gj) {
                    float ai = (I.z - I.x) * (I.w - I.y);
                    float uni = (ai + aj) - inter;   // reference op order
                    float iou = inter / uni;
                    if (iou > NMS_THR) {
                        uint32_t slot = atomicAdd(&cb[gj], 1u);
                        if (slot < ECAP)
                            atomicExch(&eb[(size_t)gj * ECAP + slot], (uint32_t)gi);
                    }
                }
            }
        }
    }
    __syncthreads();                         // vmcnt(0): all this block's atomics completed
    if (tid == 0) rankS = atomicAdd(&done2[b * 16], 1u);   // padded: one line per batch
    __syncthreads();
    if (rankS != NTPE - 1) return;
    // last block of batch: peers' cnt/edge atomics are at the coherence point;
    // this XCD's caches never cached those lines this kernel -> plain loads see them.

    const uint32_t* cb = cnt + (size_t)b * PREP;
    const uint32_t* ebw = edges + (size_t)b * PREP * ECAP;
    // cl staging: uint4 loads, 4 j per thread per round (J0/1024 = 3 rounds)
    for (int j4 = tid * 4; j4 < J0; j4 += 1024) {
        uint4 c4 = *(const uint4*)(cb + j4);
        sm.sc.cl[j4 + 0] = (uint8_t)(c4.x > 255u ? 255u : c4.x);
        sm.sc.cl[j4 + 1] = (uint8_t)(c4.y > 255u ? 255u : c4.y);
        sm.sc.cl[j4 + 2] = (uint8_t)(c4.z > 255u ? 255u : c4.z);
        sm.sc.cl[j4 + 3] = (uint8_t)(c4.w > 255u ? 255u : c4.w);
    }
    for (int j = J0 + tid; j < PREP; j += 256) {
        sm.sc.cl[j] = (uint8_t)255;          // unknown -> exact fallback path
        sm.sc.pr[j] = 0;
    }
    #pragma unroll 4
    for (int j = tid; j < J0; j += 256) {
        uint2 e01 = *(const uint2*)(ebw + (size_t)j * ECAP);     // slots 0,1
        sm.sc.pr[j] = (e01.x & 0xFFFFu) | (e01.y << 16);
    }
    __syncthreads();
    if (tid < 64) {
        int lane = tid;
        int kc = 0;
        for (int c0 = 0; c0 < NCHUNK; ++c0) {
            int base = c0 * 64;
            int j = base + lane;
            bool valid = j < PRE;
            uint64_t word = __ballot(valid);
            int cv = valid ? (int)sm.sc.cl[j] : 0;
            uint32_t prv = sm.sc.pr[j];
            uint4 ev = make_uint4(0u, 0u, 0u, 0u);
            bool manym = (cv >= 3 && cv <= ECAP);
            if (__ballot(manym)) {
                if (manym) {
                    const uint4* e128 = (const uint4*)(ebw + (size_t)j * ECAP);
                    uint4 lo = e128[0], hi = e128[1];
                    ev.x = (lo.x & 0xFFFFu) | (lo.y << 16);
                    ev.y = (lo.z & 0xFFFFu) | (lo.w << 16);
                    ev.z = (hi.x & 0xFFFFu) | (hi.y << 16);
                    ev.w = (hi.z & 0xFFFFu) | (hi.w << 16);
                }
            }
            bool same = false, supB = false;
            bool hard = valid && (cv > ECAP);
            if (valid && cv > 0 && cv <= ECAP) {
                if (cv <= 2) {
                    int p0 = (int)(prv & 0xFFFFu);
                    int p1 = (int)(prv >> 16);
                    bool s1 = (cv == 2) && (p1 >= base);
                    same = (p0 >= base) || s1;
                    if (!same) {
                        supB = ((sm.sc.km[p0 >> 6] >> (p0 & 63)) & 1ull) != 0ull;
                        if (!supB && cv == 2)
                            supB = ((sm.sc.km[p1 >> 6] >> (p1 & 63)) & 1ull) != 0ull;
                    }
                } else {
                    int es[8] = { (int)(ev.x & 0xFFFFu), (int)(ev.x >> 16),
                                  (int)(ev.y & 0xFFFFu), (int)(ev.y >> 16),
                                  (int)(ev.z & 0xFFFFu), (int)(ev.z >> 16),
                                  (int)(ev.w & 0xFFFFu), (int)(ev.w >> 16) };
                    #pragma unroll
                    for (int k = 0; k < 8; ++k)
                        if (k < cv) same = same || (es[k] >= base);
                    if (!same) {
                        #pragma unroll
                        for (int k = 0; k < 8; ++k)
                            if (k < cv && !supB)
                                supB = ((sm.sc.km[es[k] >> 6] >> (es[k] & 63)) & 1ull) != 0ull;
                    }
                }
            }
            word &= ~__ballot(supB);
            uint64_t fix = __ballot(same || hard);
            while (fix) {
                int p = __ffsll((unsigned long long)fix) - 1;
                fix &= fix - 1;
                int jp = base + p;
                int cvp = __shfl(cv, p);
                bool sup = false;
                if (cvp <= ECAP) {
                    uint32_t prp = (uint32_t)__shfl((int)prv, p);
                    uint32_t evx = (uint32_t)__shfl((int)ev.x, p);
                    uint32_t evy = (uint32_t)__shfl((int)ev.y, p);
                    uint32_t evz = (uint32_t)__shfl((int)ev.z, p);
                    uint32_t evw = (uint32_t)__shfl((int)ev.w, p);
                    int es[8];
                    if (cvp <= 2) {
                        es[0] = (int)(prp & 0xFFFFu); es[1] = (int)(prp >> 16);
                        es[2] = es[3] = es[4] = es[5] = es[6] = es[7] = 0;
                    } else {
                        es[0] = (int)(evx & 0xFFFFu); es[1] = (int)(evx >> 16);
                        es[2] = (int)(evy & 0xFFFFu); es[3] = (int)(evy >> 16);
                        es[4] = (int)(evz & 0xFFFFu); es[5] = (int)(evz >> 16);
                        es[6] = (int)(evw & 0xFFFFu); es[7] = (int)(evw >> 16);
                    }
                    #pragma unroll
                    for (int k = 0; k < 8; ++k) {
                        if (k < cvp && !sup) {
                            int e = es[k];
                            bool kept = (e >= base)
                                ? (((word >> (e - base)) & 1ull) != 0ull)
                                : (((sm.sc.km[e >> 6] >> (e & 63)) & 1ull) != 0ull);
                            sup = sup || kept;
                        }
                    }
                } else {
                    float4 J = bx[jp];
                    bool any = false;
                    for (int t2 = lane; t2 < kc; t2 += 64)
                        if (iou_of(bx[sm.sc.list[t2]], J) > NMS_THR) any = true;
                    if (lane < p && ((word >> lane) & 1ull))
                        if (iou_of(bx[base + lane], J) > NMS_THR) any = true;
                    sup = (__ballot(any) != 0ull);
                }
                if (sup) word &= ~(1ull << p);
            }
            sm.sc.km[c0] = word;
            int pos = kc + __popcll(word & ((1ull << lane) - 1ull));
            if (((word >> lane) & 1ull) && pos < OUT_CNT) sm.sc.list[pos] = (uint16_t)j;
            kc += __popcll(word);
            if (kc >= OUT_CNT) { kc = OUT_CNT; break; }
        }
        if (lane == 0) sm.sc.kcs = kc;
    }
    __syncthreads();
    int kc = sm.sc.kcs;
    float4* ob = (float4*)(out) + (size_t)b * OUT_CNT;
    for (int r = tid; r < OUT_CNT; r += 256) {
        float4 o = make_float4(0.f, 0.f, 0.f, 0.f);
        if (r < kc) o = bx[sm.sc.list[r]];
        ob[r] = o;
    }
}

extern "C" void kernel_launch(void* const* d_in, const int* in_sizes, int n_in,
                              void* d_out, int out_size, void* d_ws, size_t ws_size,
                              hipStream_t stream) {
    const float* probs   = (const float*)d_in[0];
    const float* rpnbbox = (const float*)d_in[1];
    const float* anchors = (const float*)d_in[2];
    float* out = (float*)d_out;
    char* ws = (char*)d_ws;

    uint32_t* pref  = (uint32_t*)(ws + OFF_PREF);
    uint32_t* lcnts = (uint32_t*)(ws + OFF_LCNTS);
    uint64_t* slab  = (uint64_t*)(ws + OFF_SLAB);
    uint32_t* cnt   = (uint32_t*)(ws + OFF_CNT);
    uint32_t* done2 = (uint32_t*)(ws + OFF_DONE2);
    float*    boxes = (float*)(ws + OFF_BOXES);
    uint32_t* edges = (uint32_t*)(ws + OFF_EDGES);

    k_pass1<<<dim3(NSUB, NBATCH), 256, 0, stream>>>(probs, pref, lcnts, slab,
                                                    (uint4*)(ws + OFF_CNT));
    k_binsel<<<dim3(128, NBATCH), 256, 0, stream>>>(probs, pref, lcnts, slab,
                                                    rpnbbox, anchors, boxes);
    k_edgescan<<<dim3(NTPE, NBATCH), 256, 0, stream>>>(boxes, cnt, edges, done2, out);
}